// Round 15
// baseline (975.424 us; speedup 1.0000x reference)
//
#include <hip/hip_runtime.h>
#include <hip/hip_bf16.h>

// GraphCAD forward on MI355X. All float I/O is f32.
// R21->R22: LDS diet was null - occupancy (39%) is throttled by barrier
// waits, not residency. So cut per-tile sync cost: the sred LDS round-trip
// is unnecessary because for fixed ty the 16 tx lanes are 16 CONSECUTIVE
// LANES OF ONE WAVE -> the tx-sum is an intra-wave butterfly (shfl_xor
// 1,2,4,8). Epilogue now: compute part[r], 4x4 shfl_xor reduce, lanes tx<4
// sample slot 4*ty+tx (64 parallel sampling lanes, no serial 16-read loop).
// Tile loop: 3 barriers -> 2. f32 sum-order change ~1e-6, under the
// FIXTH=2e-3 / k_fix-f64 guard. All else identical to R21 (964us).

#define D 64
#define BSZ 16
#define NPG 4096
#define NN (BSZ * NPG)   // 65536 nodes
#define NE (NN * 16)     // 1048576 edges
#define NL 2
#define NTILE (NE / 64)  // 16384

#define FIXTH 2e-3f
#define FLAGCAP 65536

// output layout (elements, f32)
#define OUT_X  0u
#define OUT_EW 4194304u
#define OUT_C  5242880u
#define OUT_XL 5243904u
#define OUT_CL 9438208u
#define OUT_PA 9439232u

__device__ __forceinline__ void atomAdd64(double* p, double v) { unsafeAtomicAdd(p, v); }

// ================= CSR build (dst is a static input; rebuilt per call) ======
__global__ __launch_bounds__(256) void k_deg(const int* __restrict__ edst,
                                             int* __restrict__ cnt) {
    int stride = gridDim.x * 256;
    for (int e = blockIdx.x * 256 + threadIdx.x; e < NE; e += stride)
        atomicAdd(&cnt[edst[e]], 1);
}

__global__ __launch_bounds__(256) void k_scan1(const int* __restrict__ cnt,
                                               int* __restrict__ rowptr,
                                               int* __restrict__ bsum) {
    __shared__ int sd[256];
    const int b = blockIdx.x, t = threadIdx.x;
    const int v = cnt[b * 256 + t];
    sd[t] = v;
    __syncthreads();
    for (int off = 1; off < 256; off <<= 1) {
        int tmp = (t >= off) ? sd[t - off] : 0;
        __syncthreads();
        sd[t] += tmp;
        __syncthreads();
    }
    rowptr[b * 256 + t] = sd[t] - v;  // exclusive
    if (t == 255) bsum[b] = sd[255];
}

__global__ __launch_bounds__(256) void k_scan2(int* __restrict__ bsum) {
    __shared__ int sd[256];
    const int t = threadIdx.x;
    const int v = bsum[t];
    sd[t] = v;
    __syncthreads();
    for (int off = 1; off < 256; off <<= 1) {
        int tmp = (t >= off) ? sd[t - off] : 0;
        __syncthreads();
        sd[t] += tmp;
        __syncthreads();
    }
    bsum[t] = sd[t] - v;  // exclusive
}

__global__ __launch_bounds__(256) void k_scan3(const int* __restrict__ bsum,
                                               int* __restrict__ rowptr,
                                               int* __restrict__ cursor) {
    const int i = blockIdx.x * 256 + threadIdx.x;
    const int r = rowptr[i] + bsum[blockIdx.x];
    rowptr[i] = r;
    cursor[i] = r;
    if (i == 0) rowptr[NN] = NE;
}

// fill CSR: slot -> original edge (eord), src (src_csr), dst (dst_csr).
__global__ __launch_bounds__(256) void k_fill(const int* __restrict__ esrc,
                                              const int* __restrict__ edst,
                                              int* __restrict__ cursor,
                                              int* __restrict__ eord,
                                              int* __restrict__ src_csr,
                                              int* __restrict__ dst_csr) {
    int stride = gridDim.x * 256;
    for (int e = blockIdx.x * 256 + threadIdx.x; e < NE; e += stride) {
        const int d = edst[e];
        int pos = atomicAdd(&cursor[d], 1);
        eord[pos] = e;
        src_csr[pos] = esrc[e];
        dst_csr[pos] = d;
    }
}

// ---- initial centroid: per-graph mean of x (f32 in, f64 out), 8 blocks/graph
__global__ __launch_bounds__(256) void k_centroid0(const float* __restrict__ xin,
                                                   double* __restrict__ c64) {
    const int g = blockIdx.x >> 3, sub = blockIdx.x & 7, tid = threadIdx.x;
    const int r = tid >> 6, f = tid & 63;
    __shared__ double cr[4][D];
    double s = 0.0;
    for (int k = 0; k < NPG / 8 / 4; ++k) {
        size_t n = (size_t)g * NPG + (size_t)(sub * (NPG / 8) + 4 * k + r);
        s += (double)xin[n * D + f];
    }
    cr[r][f] = s;
    __syncthreads();
    if (tid < D)
        atomAdd64(&c64[g * D + tid],
                  (cr[0][tid] + cr[1][tid] + cr[2][tid] + cr[3][tid]) * (1.0 / NPG));
}

// ---- qb = c @ W1b, qc = c @ W1c (per graph, f64) ----
__global__ __launch_bounds__(256) void k_qbc(const double* __restrict__ c64,
                                             const float* __restrict__ epW1,
                                             double* __restrict__ qb, double* __restrict__ qc) {
    int gj = blockIdx.x * 256 + threadIdx.x;
    if (gj >= BSZ * D) return;
    int g = gj >> 6, j = gj & 63;
    double sb = 0.0, sc = 0.0;
#pragma unroll
    for (int i = 0; i < D; ++i) {
        double cv = c64[g * D + i];
        sb += cv * (double)epW1[(D + i) * D + j];
        sc += cv * (double)epW1[(2 * D + i) * D + j];
    }
    qb[gj] = sb;
    qc[gj] = sc;
}

// ---- P'_b = x@W1b - qb[g], P'_c = x@W1c - qc[g]; f32 compute/store ----
// f32 shift ~1e-6 on Pb/Pc; k_edge and k_fix both read these same values,
// so decisions stay consistent; |margin|<FIXTH edges go to k_fix regardless.
template <int LAYER>
__global__ __launch_bounds__(256) void k_P(const float* __restrict__ xin,
                                           const float* __restrict__ x32,
                                           const float* __restrict__ epW1,
                                           const double* __restrict__ qb,
                                           const double* __restrict__ qc,
                                           float* __restrict__ Pb, float* __restrict__ Pc,
                                           double* __restrict__ bnacc) {
    if (blockIdx.x == 0 && threadIdx.x < 128) bnacc[threadIdx.x] = 0.0;
    __shared__ float wb[D * D];
    __shared__ float wc[D * D];
    __shared__ float xrow[4][D];
    int tid = threadIdx.x, w = tid >> 6, j = tid & 63;
    for (int idx = tid; idx < D * D; idx += 256) {
        int i = idx >> 6, c = idx & 63;
        wb[idx] = epW1[(D + i) * D + c];
        wc[idx] = epW1[(2 * D + i) * D + c];
    }
    __syncthreads();
    for (int grp = blockIdx.x; grp < NN / 4; grp += gridDim.x) {
        size_t n = (size_t)grp * 4 + w;
        xrow[w][j] = (LAYER == 0) ? xin[n * D + j] : x32[n * D + j];
        __syncthreads();
        float pb = 0.0f, pc = 0.0f;
#pragma unroll
        for (int i = 0; i < D; ++i) {
            const float xv = xrow[w][i];
            pb += xv * wb[i * D + j];
            pc += xv * wc[i * D + j];
        }
        const int g = (int)(n >> 12);
        Pb[n * D + j] = pb - (float)qb[g * D + j];
        Pc[n * D + j] = pc - (float)qc[g * D + j];
        __syncthreads();
    }
}

// ---- edge scorer, CSR order: all-f32 tile GEMM + sample; near-threshold
// ---- edges (|score+g| < FIXTH) deferred to k_fix for exact f64 decision.
// LDS: A f32 [64][64] 16KB, W f32 [64][64] 16KB. 2 barriers/tile; the
// tx-sum is an intra-wave 16-lane shfl butterfly (no sred, no 3rd barrier).
template <int LAYER>
__global__ __launch_bounds__(256, 4) void k_edge(const float* __restrict__ xsrc,
                                                 const int* __restrict__ src_csr,
                                                 const int* __restrict__ dst_csr,
                                                 const int* __restrict__ eord,
                                                 const float* __restrict__ ewin,
                                                 float* __restrict__ ew_csr,
                                                 const float* __restrict__ unoise,
                                                 const float* __restrict__ epW1,
                                                 const float* __restrict__ epb1,
                                                 const float* __restrict__ epW2,
                                                 const float* __restrict__ epb2,
                                                 const float* __restrict__ alphap,
                                                 const float* __restrict__ Pb32,
                                                 const float* __restrict__ Pc32,
                                                 int* __restrict__ flagcnt,
                                                 int* __restrict__ flaglist,
                                                 float* __restrict__ out) {
    const int t = threadIdx.x;
    const int tx = t & 15, ty = t >> 4;

    __shared__ __align__(16) float ldsA[64 * 64];  // |dx| [dim][slot]
    __shared__ __align__(16) float ldsW[64 * 64];  // W1a [k][j]

    for (int idx = t; idx < D * D; idx += 256) {
        ldsW[idx] = epW1[idx];  // [k][j] layout matches epW1 row-major
    }
    float b1f[4], w2f[4];
#pragma unroll
    for (int c = 0; c < 4; ++c) {
        b1f[c] = epb1[4 * tx + c];
        w2f[c] = epW2[4 * tx + c];
    }
    const float b2v = epb2[0];
    const float alpha = alphap[0];
    __syncthreads();

    const int eloc = t >> 2, q = t & 3;

    for (int tile = blockIdx.x; tile < NTILE; tile += gridDim.x) {
        const int base = tile * 64;

        // ---- stage |x_d - x_s| (f32, transposed). d-rows run-repeat (L1). --
        {
            const int pos = base + eloc;
            const int s = src_csr[pos], d = dst_csr[pos];
            const float* rs = xsrc + (size_t)s * D + q * 16;
            const float* rd = xsrc + (size_t)d * D + q * 16;
#pragma unroll
            for (int c = 0; c < 4; ++c) {
                const float4 fd = *(const float4*)(rd + 4 * c);
                const float4 fs = *(const float4*)(rs + 4 * c);
                const int dim = q * 16 + 4 * c;
                ldsA[(dim + 0) * 64 + eloc] = fabsf(fd.x - fs.x);
                ldsA[(dim + 1) * 64 + eloc] = fabsf(fd.y - fs.y);
                ldsA[(dim + 2) * 64 + eloc] = fabsf(fd.z - fs.z);
                ldsA[(dim + 3) * 64 + eloc] = fabsf(fd.w - fs.w);
            }
        }
        __syncthreads();

        // ---- 64x64x64 GEMM: f32 inputs, f32 accumulate, 4x4 per thread ----
        float acc[4][4];
#pragma unroll
        for (int r = 0; r < 4; ++r)
#pragma unroll
            for (int c = 0; c < 4; ++c) acc[r][c] = 0.0f;

#pragma unroll 4
        for (int k = 0; k < 64; ++k) {
            const float4 af = *(const float4*)&ldsA[k * 64 + 4 * ty];
            const float4 wf = *(const float4*)&ldsW[k * 64 + 4 * tx];
            const float av[4] = {af.x, af.y, af.z, af.w};
            const float wv[4] = {wf.x, wf.y, wf.z, wf.w};
#pragma unroll
            for (int r = 0; r < 4; ++r)
#pragma unroll
                for (int c = 0; c < 4; ++c) acc[r][c] += av[r] * wv[c];
        }

        // ---- epilogue: + P' terms, +b1, relu, * w2; butterfly over tx ----
        float part[4];
#pragma unroll
        for (int r = 0; r < 4; ++r) {
            const int pos = base + 4 * ty + r;
            const int s = src_csr[pos], d = dst_csr[pos];
            const float4 pb = *(const float4*)(Pb32 + (size_t)d * D + 4 * tx);
            const float4 pc = *(const float4*)(Pc32 + (size_t)s * D + 4 * tx);
            float p = 0.0f;
            float h;
            h = acc[r][0] + pb.x + pc.x + b1f[0];
            if (h > 0.0f) p += h * w2f[0];
            h = acc[r][1] + pb.y + pc.y + b1f[1];
            if (h > 0.0f) p += h * w2f[1];
            h = acc[r][2] + pb.z + pc.z + b1f[2];
            if (h > 0.0f) p += h * w2f[2];
            h = acc[r][3] + pb.w + pc.w + b1f[3];
            if (h > 0.0f) p += h * w2f[3];
            part[r] = p;
        }
        // tx lanes of one ty-group are 16 consecutive lanes of one wave:
#pragma unroll
        for (int off = 1; off < 16; off <<= 1) {
#pragma unroll
            for (int r = 0; r < 4; ++r) part[r] += __shfl_xor(part[r], off);
        }

        // ---- sample: lanes tx<4 each own slot 4*ty + tx ----
        if (tx < 4) {
            const int pos = base + 4 * ty + tx;
            const float sc_ = part[tx] + b2v;
            const int e = eord[pos];
            const float u = unoise[(size_t)LAYER * NE + e];
            const float gn = logf(u) - log1pf(-u);
            const float mar = sc_ + gn;  // decision margin; samp == (mar > 0)
            bool deferred = false;
            if (fabsf(mar) < FIXTH) {
                int slot = atomicAdd(flagcnt, 1);
                if (slot < FLAGCAP) {
                    flaglist[slot] = pos;
                    deferred = true;  // k_fix decides + writes this edge
                }
            }
            if (!deferred) {
                const float pre = 1.0f / (1.0f + expf(-sc_));
                const bool samp = mar > 0.0f;
                const float ewo = (LAYER == 0) ? ewin[e] : ew_csr[pos];
                const float ewn = samp ? alpha * ewo + (1.0f - alpha) * pre : 0.0f;
                ew_csr[pos] = ewn;
                if (LAYER == NL - 1) {
                    out[OUT_EW + (size_t)e] = ewn;
                    out[OUT_PA + (size_t)e] = pre;
                }
            }
        }
        __syncthreads();  // protect ldsA from next tile's staging
    }
}

// ---- exact f64 re-decision for near-threshold edges (one wave per edge) ----
template <int LAYER>
__global__ __launch_bounds__(256) void k_fix(const float* __restrict__ xsrc,
                                             const int* __restrict__ src_csr,
                                             const int* __restrict__ dst_csr,
                                             const int* __restrict__ eord,
                                             const float* __restrict__ ewin,
                                             float* __restrict__ ew_csr,
                                             const float* __restrict__ unoise,
                                             const float* __restrict__ epW1,
                                             const float* __restrict__ epb1,
                                             const float* __restrict__ epW2,
                                             const float* __restrict__ epb2,
                                             const float* __restrict__ alphap,
                                             const float* __restrict__ Pb32,
                                             const float* __restrict__ Pc32,
                                             const int* __restrict__ flagcnt,
                                             const int* __restrict__ flaglist,
                                             float* __restrict__ out) {
    const int n = min(flagcnt[0], FLAGCAP);
    __shared__ float dxs[4][D];
    const int w = threadIdx.x >> 6, lane = threadIdx.x & 63;
    const int nw = gridDim.x * 4;
    for (int i = blockIdx.x * 4 + w; i < n; i += nw) {
        const int pos = flaglist[i];
        const int s = src_csr[pos], d = dst_csr[pos];
        // |dx| from the same f32 inputs the main kernel staged
        dxs[w][lane] = fabsf(xsrc[(size_t)d * D + lane] - xsrc[(size_t)s * D + lane]);
        // wave-internal broadcast (same-wave DS in-order)
        double h = 0.0;
#pragma unroll
        for (int k = 0; k < D; ++k) h += (double)dxs[w][k] * (double)epW1[k * D + lane];
        h += (double)Pb32[(size_t)d * D + lane] + (double)Pc32[(size_t)s * D + lane] +
             (double)epb1[lane];
        double part = (h > 0.0) ? h * (double)epW2[lane] : 0.0;
#pragma unroll
        for (int off = 32; off; off >>= 1) part += __shfl_xor(part, off);
        if (lane == 0) {
            const double sc_ = part + (double)epb2[0];
            const int e = eord[pos];
            const double u = (double)unoise[(size_t)LAYER * NE + e];
            const double gn = log(u) - log1p(-u);
            const double pre = 1.0 / (1.0 + exp(-sc_));
            const bool samp = (sc_ + gn) > 0.0;
            const double ewo = (LAYER == 0) ? (double)ewin[e] : (double)ew_csr[pos];
            const double alpha = (double)alphap[0];
            const double ewn = samp ? alpha * ewo + (1.0 - alpha) * pre : 0.0;
            ew_csr[pos] = (float)ewn;
            if (LAYER == NL - 1) {
                out[OUT_EW + (size_t)e] = (float)ewn;
                out[OUT_PA + (size_t)e] = (float)pre;
            }
        }
    }
}

// ---- node update: CSR gather (row-parallel loads) + GIN mlp + BN partials --
// Lane = (slot e=0..3, quarter q=0..15). First 16 edges: 4 float4-load
// instructions x 4 rows each, issued back-to-back. f64 acc per (slot,4dims);
// tree-reduce slots (2x shfl_xor); + self; f64 matvec; xh stored f32
// (BN stats still from unrounded f64 h). bnacc block-reduced in LDS first.
template <int LAYER>
__global__ __launch_bounds__(256) void k_nodeup(const float* __restrict__ xsrc,
                                                const float* __restrict__ ew_csr,
                                                const int* __restrict__ src_csr,
                                                const int* __restrict__ rowptr,
                                                const float* __restrict__ ginW,
                                                const float* __restrict__ ginB,
                                                float* __restrict__ xh,
                                                double* __restrict__ bnacc) {
    __shared__ float wg[D * D];
    __shared__ double rowbuf[4][D];
    __shared__ double bn1[4][D];
    __shared__ double bn2[4][D];
    const int t = threadIdx.x, w = t >> 6, lane = t & 63;
    const int e = lane >> 4, q = lane & 15;  // slot, quarter (dims 4q..4q+3)
    for (int idx = t; idx < D * D; idx += 256) wg[idx] = ginW[LAYER * D * D + idx];
    const double bj = (double)ginB[LAYER * D + lane];
    __syncthreads();
    double s1 = 0.0, s2 = 0.0;
    const int nwaves = gridDim.x * 4;
    for (int n = blockIdx.x * 4 + w; n < NN; n += nwaves) {
        const int rs = rowptr[n], re = rowptr[n + 1];
        const int deg = re - rs;
        // ---- first 16 edges: 4 masked slots x 4 chunks, all loads up front
        const int i0 = rs + ((e < deg) ? e : 0);
        const int i1 = rs + ((4 + e < deg) ? 4 + e : 0);
        const int i2 = rs + ((8 + e < deg) ? 8 + e : 0);
        const int i3 = rs + ((12 + e < deg) ? 12 + e : 0);
        const float w0 = (e < deg) ? ew_csr[i0] : 0.f;
        const float w1 = (4 + e < deg) ? ew_csr[i1] : 0.f;
        const float w2 = (8 + e < deg) ? ew_csr[i2] : 0.f;
        const float w3 = (12 + e < deg) ? ew_csr[i3] : 0.f;
        const int s0 = src_csr[i0], s1_ = src_csr[i1];
        const int s2_ = src_csr[i2], s3_ = src_csr[i3];
        const float4 r0 = *(const float4*)(xsrc + (size_t)s0 * D + 4 * q);
        const float4 r1 = *(const float4*)(xsrc + (size_t)s1_ * D + 4 * q);
        const float4 r2 = *(const float4*)(xsrc + (size_t)s2_ * D + 4 * q);
        const float4 r3 = *(const float4*)(xsrc + (size_t)s3_ * D + 4 * q);
        const float4 rf = *(const float4*)(xsrc + (size_t)n * D + 4 * q);  // self
        double a0 = (double)w0 * (double)r0.x;
        double a1 = (double)w0 * (double)r0.y;
        double a2 = (double)w0 * (double)r0.z;
        double a3 = (double)w0 * (double)r0.w;
        a0 += (double)w1 * (double)r1.x;
        a1 += (double)w1 * (double)r1.y;
        a2 += (double)w1 * (double)r1.z;
        a3 += (double)w1 * (double)r1.w;
        a0 += (double)w2 * (double)r2.x;
        a1 += (double)w2 * (double)r2.y;
        a2 += (double)w2 * (double)r2.z;
        a3 += (double)w2 * (double)r2.w;
        a0 += (double)w3 * (double)r3.x;
        a1 += (double)w3 * (double)r3.y;
        a2 += (double)w3 * (double)r3.z;
        a3 += (double)w3 * (double)r3.w;
        // ---- tail: edges beyond 16, masked chunks of 4 (wave-uniform bound)
        for (int k = rs + 16; k < re; k += 4) {
            const int kk = k + e;
            const bool v = kk < re;
            const float wt = v ? ew_csr[kk] : 0.f;
            const int st = src_csr[v ? kk : rs];
            const float4 rt = *(const float4*)(xsrc + (size_t)st * D + 4 * q);
            a0 += (double)wt * (double)rt.x;
            a1 += (double)wt * (double)rt.y;
            a2 += (double)wt * (double)rt.z;
            a3 += (double)wt * (double)rt.w;
        }
        // ---- tree-reduce the 4 slots (lanes differing in bits 4,5) ----
        a0 += __shfl_xor(a0, 16);
        a1 += __shfl_xor(a1, 16);
        a2 += __shfl_xor(a2, 16);
        a3 += __shfl_xor(a3, 16);
        a0 += __shfl_xor(a0, 32);
        a1 += __shfl_xor(a1, 32);
        a2 += __shfl_xor(a2, 32);
        a3 += __shfl_xor(a3, 32);
        // ---- + self, publish to rowbuf (same-wave DS in-order) ----
        if (e == 0) {
            rowbuf[w][4 * q + 0] = a0 + (double)rf.x;
            rowbuf[w][4 * q + 1] = a1 + (double)rf.y;
            rowbuf[w][4 * q + 2] = a2 + (double)rf.z;
            rowbuf[w][4 * q + 3] = a3 + (double)rf.w;
        }
        // ---- GIN matvec (f64) ----
        double h = bj;
#pragma unroll
        for (int i = 0; i < D; ++i) h += rowbuf[w][i] * (double)wg[i * D + lane];
        h = h > 0.0 ? h : 0.0;
        xh[(size_t)n * D + lane] = (float)h;
        s1 += h;
        s2 += h * h;
    }
    // ---- block-level reduce, then 2 atomics per lane-column per block ----
    bn1[w][lane] = s1;
    bn2[w][lane] = s2;
    __syncthreads();
    if (w == 0) {
        atomAdd64(&bnacc[lane], bn1[0][lane] + bn1[1][lane] + bn1[2][lane] + bn1[3][lane]);
        atomAdd64(&bnacc[64 + lane], bn2[0][lane] + bn2[1][lane] + bn2[2][lane] + bn2[3][lane]);
    }
}

// ---- BN finalize ----
__global__ __launch_bounds__(64) void k_bnfin(int layer, const float* __restrict__ gamma,
                                              const float* __restrict__ beta,
                                              const double* __restrict__ bnacc,
                                              double* __restrict__ bnsc) {
    int j = threadIdx.x;
    double mu = bnacc[j] * (1.0 / NN);
    double var = bnacc[64 + j] * (1.0 / NN) - mu * mu;
    double sc = (double)gamma[layer * D + j] / sqrt(var + 1e-5);
    bnsc[j] = sc;
    bnsc[64 + j] = (double)beta[layer * D + j] - mu * sc;
}

// ---- BN apply -> x32 (f64 affine, single rounding; final out at layer 1) --
template <int LAYER>
__global__ __launch_bounds__(256) void k_bnapply(const double* __restrict__ bnsc,
                                                 const float* __restrict__ xh,
                                                 float* __restrict__ x32,
                                                 float* __restrict__ out) {
    size_t stride = (size_t)gridDim.x * 256;
    for (size_t i = (size_t)blockIdx.x * 256 + threadIdx.x; i < (size_t)NN * D; i += stride) {
        int j = (int)(i & 63);
        const float v = (float)(bnsc[j] * (double)xh[i] + bnsc[64 + j]);
        x32[i] = v;
        if (LAYER == NL - 1) out[OUT_X + i] = v;
    }
}

// ---- attention pooling, parallelized: 4 kernels (x in f32, math f64) ----
__global__ __launch_bounds__(256) void k_att1(const float* __restrict__ x32,
                                              const double* __restrict__ c64,
                                              double* __restrict__ sc,
                                              double* __restrict__ bmax) {
    const int blk = blockIdx.x, t = threadIdx.x, w = t >> 6, lane = t & 63;
    const int g = blk >> 6;
    __shared__ double wmax[4];
    const double cj = c64[g * D + lane];
    double locmax = -1e300;
    for (int m = 0; m < 16; ++m) {
        const int n = blk * 64 + w * 16 + m;
        double v = (double)x32[(size_t)n * D + lane] * cj;
#pragma unroll
        for (int off = 32; off; off >>= 1) v += __shfl_xor(v, off);
        if (lane == 0) sc[n] = v;
        locmax = fmax(locmax, v);
    }
    if (lane == 0) wmax[w] = locmax;
    __syncthreads();
    if (t == 0) bmax[blk] = fmax(fmax(wmax[0], wmax[1]), fmax(wmax[2], wmax[3]));
}

__global__ __launch_bounds__(64) void k_att2(const double* __restrict__ bmax,
                                             double* __restrict__ mxg,
                                             double* __restrict__ num,
                                             double* __restrict__ den) {
    const int g = blockIdx.x, t = threadIdx.x;
    double m = bmax[g * 64 + t];
#pragma unroll
    for (int off = 32; off; off >>= 1) m = fmax(m, __shfl_xor(m, off));
    if (t == 0) {
        mxg[g] = m;
        den[g] = 0.0;
    }
    num[g * D + t] = 0.0;
}

__global__ __launch_bounds__(256) void k_att3(const float* __restrict__ x32,
                                              const double* __restrict__ sc,
                                              const double* __restrict__ mxg,
                                              double* __restrict__ num,
                                              double* __restrict__ den) {
    const int blk = blockIdx.x, t = threadIdx.x, w = t >> 6, lane = t & 63;
    const int g = blk >> 6;
    __shared__ double cp[4][D];
    __shared__ double wes[4];
    const double mx = mxg[g];
    double accj = 0.0, esum = 0.0;
    for (int m = 0; m < 16; ++m) {
        const int n = blk * 64 + w * 16 + m;
        const double e = exp(sc[n] - mx);
        accj += e * (double)x32[(size_t)n * D + lane];
        esum += e;
    }
    cp[w][lane] = accj;
    if (lane == 0) wes[w] = esum;
    __syncthreads();
    if (t < D) {
        atomAdd64(&num[g * D + t], cp[0][t] + cp[1][t] + cp[2][t] + cp[3][t]);
        if (t == 0) atomAdd64(&den[g], wes[0] + wes[1] + wes[2] + wes[3]);
    }
}

__global__ __launch_bounds__(64) void k_att4(const double* __restrict__ num,
                                             const double* __restrict__ den,
                                             double* __restrict__ c64) {
    const int g = blockIdx.x, t = threadIdx.x;
    c64[g * D + t] = num[g * D + t] / den[g];
}

// ---- head: relu(x@W1+b1)@W2+b2 for all nodes + 16 centroid rows (f32) ----
__global__ __launch_bounds__(256) void k_head(const float* __restrict__ x32,
                                              const double* __restrict__ c64,
                                              const float* __restrict__ hW1,
                                              const float* __restrict__ hb1,
                                              const float* __restrict__ hW2,
                                              const float* __restrict__ hb2,
                                              float* __restrict__ out) {
    __shared__ float w1[D * D];
    __shared__ float w2[D * D];
    __shared__ float xr[4][D];
    __shared__ float hr[4][D];
    int tid = threadIdx.x, w = tid >> 6, j = tid & 63;
    for (int idx = tid; idx < D * D; idx += 256) {
        w1[idx] = hW1[idx];
        w2[idx] = hW2[idx];
    }
    const float b1j = hb1[j];
    const float b2j = hb2[j];
    __syncthreads();
    const int ROWS = NN + BSZ;
    for (int grp = blockIdx.x; grp * 4 < ROWS; grp += gridDim.x) {
        int r = grp * 4 + w;
        bool valid = r < ROWS;
        float xv = 0.f;
        if (valid)
            xv = (r < NN) ? x32[(size_t)r * D + j] : (float)c64[(size_t)(r - NN) * D + j];
        xr[w][j] = xv;
        __syncthreads();
        if (valid) {
            float h = b1j;
#pragma unroll
            for (int i = 0; i < D; ++i) h += xr[w][i] * w1[i * D + j];
            hr[w][j] = h > 0.f ? h : 0.f;
        }
        __syncthreads();
        if (valid) {
            float o = b2j;
#pragma unroll
            for (int i = 0; i < D; ++i) o += hr[w][i] * w2[i * D + j];
            if (r < NN) {
                out[OUT_XL + (size_t)r * D + j] = o;
            } else {
                size_t cr = (size_t)(r - NN) * D + j;
                out[OUT_CL + cr] = o;
                out[OUT_C + cr] = (float)c64[cr];
            }
        }
        __syncthreads();
    }
}

extern "C" void kernel_launch(void* const* d_in, const int* in_sizes, int n_in,
                              void* d_out, int out_size, void* d_ws, size_t ws_size,
                              hipStream_t stream) {
    const float* xin    = (const float*)d_in[0];
    const int*   ei     = (const int*)d_in[1];
    const float* ewin   = (const float*)d_in[2];
    const float* unoise = (const float*)d_in[5];
    const float* epW1   = (const float*)d_in[6];
    const float* epb1   = (const float*)d_in[7];
    const float* epW2   = (const float*)d_in[8];
    const float* epb2   = (const float*)d_in[9];
    const float* alphap = (const float*)d_in[10];
    const float* ginW   = (const float*)d_in[11];
    const float* ginB   = (const float*)d_in[12];
    const float* bng    = (const float*)d_in[13];
    const float* bnb    = (const float*)d_in[14];
    const float* hW1    = (const float*)d_in[15];
    const float* hb1    = (const float*)d_in[16];
    const float* hW2    = (const float*)d_in[17];
    const float* hb2    = (const float*)d_in[18];
    float* out = (float*)d_out;
    const int* esrc = ei;
    const int* edst = ei + NE;

    char* ws = (char*)d_ws;
    const size_t SZ4 = (size_t)NN * D * sizeof(float);  // 16MB
    // Pb (k_P->k_edge/k_fix) and xh (k_nodeup->k_bnapply): disjoint live ranges.
    float* Pb32 = (float*)(ws);
    float* xh32 = Pb32;  // alias
    float* Pc32 = (float*)(ws + SZ4);
    float* x32  = (float*)(ws + 2 * SZ4);
    float* ew_csr = (float*)(ws + 3 * SZ4);                       // NE*4 = 4MB
    double* sc  = (double*)(ws + 3 * SZ4 + (size_t)NE * 4);       // NN*8
    char*  p    = ws + 3 * SZ4 + (size_t)NE * 4 + (size_t)NN * 8;
    double* c64  = (double*)p;          p += BSZ * D * 8;
    double* qb   = (double*)p;          p += BSZ * D * 8;
    double* qc   = (double*)p;          p += BSZ * D * 8;
    double* bnacc = (double*)p;         p += 128 * 8;
    double* bnsc  = (double*)p;         p += 128 * 8;
    double* bmax  = (double*)p;         p += 1024 * 8;
    double* mxg   = (double*)p;         p += 16 * 8;
    double* num   = (double*)p;         p += BSZ * D * 8;
    double* den   = (double*)p;         p += 16 * 8;
    // CSR
    int* cnt     = (int*)p;             p += (size_t)NN * 4;
    int* rowptr  = (int*)p;             p += (size_t)(NN + 1) * 4 + 4;
    int* cursor  = (int*)p;             p += (size_t)NN * 4;
    int* bsum    = (int*)p;             p += 256 * 4;
    int* eord    = (int*)p;             p += (size_t)NE * 4;
    int* src_csr = (int*)p;             p += (size_t)NE * 4;
    int* dst_csr = (int*)p;             p += (size_t)NE * 4;
    // near-threshold fixup list
    int* flagcnt  = (int*)p;            p += 8;
    int* flaglist = (int*)p;            p += (size_t)FLAGCAP * 4;

    // ---- CSR build (dst static) ----
    hipMemsetAsync(cnt, 0, (size_t)NN * 4, stream);
    k_deg<<<1024, 256, 0, stream>>>(edst, cnt);
    k_scan1<<<256, 256, 0, stream>>>(cnt, rowptr, bsum);
    k_scan2<<<1, 256, 0, stream>>>(bsum);
    k_scan3<<<256, 256, 0, stream>>>(bsum, rowptr, cursor);
    k_fill<<<1024, 256, 0, stream>>>(esrc, edst, cursor, eord, src_csr, dst_csr);

    hipMemsetAsync(c64, 0, (size_t)BSZ * D * 8, stream);
    k_centroid0<<<BSZ * 8, 256, 0, stream>>>(xin, c64);

    // ---------------- layer 0 ----------------
    k_qbc<<<4, 256, 0, stream>>>(c64, epW1, qb, qc);
    k_P<0><<<2048, 256, 0, stream>>>(xin, x32, epW1, qb, qc, Pb32, Pc32, bnacc);
    hipMemsetAsync(flagcnt, 0, 4, stream);
    k_edge<0><<<2048, 256, 0, stream>>>(xin, src_csr, dst_csr, eord, ewin, ew_csr, unoise,
                                        epW1, epb1, epW2, epb2, alphap, Pb32, Pc32,
                                        flagcnt, flaglist, out);
    k_fix<0><<<64, 256, 0, stream>>>(xin, src_csr, dst_csr, eord, ewin, ew_csr, unoise,
                                     epW1, epb1, epW2, epb2, alphap, Pb32, Pc32,
                                     flagcnt, flaglist, out);
    k_nodeup<0><<<2048, 256, 0, stream>>>(xin, ew_csr, src_csr, rowptr, ginW, ginB,
                                          xh32, bnacc);
    k_bnfin<<<1, 64, 0, stream>>>(0, bng, bnb, bnacc, bnsc);
    k_bnapply<0><<<2048, 256, 0, stream>>>(bnsc, xh32, x32, out);
    k_att1<<<1024, 256, 0, stream>>>(x32, c64, sc, bmax);
    k_att2<<<16, 64, 0, stream>>>(bmax, mxg, num, den);
    k_att3<<<1024, 256, 0, stream>>>(x32, sc, mxg, num, den);
    k_att4<<<16, 64, 0, stream>>>(num, den, c64);

    // ---------------- layer 1 ----------------
    k_qbc<<<4, 256, 0, stream>>>(c64, epW1, qb, qc);
    k_P<1><<<2048, 256, 0, stream>>>(xin, x32, epW1, qb, qc, Pb32, Pc32, bnacc);
    hipMemsetAsync(flagcnt, 0, 4, stream);
    k_edge<1><<<2048, 256, 0, stream>>>(x32, src_csr, dst_csr, eord, ewin, ew_csr, unoise,
                                        epW1, epb1, epW2, epb2, alphap, Pb32, Pc32,
                                        flagcnt, flaglist, out);
    k_fix<1><<<64, 256, 0, stream>>>(x32, src_csr, dst_csr, eord, ewin, ew_csr, unoise,
                                     epW1, epb1, epW2, epb2, alphap, Pb32, Pc32,
                                     flagcnt, flaglist, out);
    k_nodeup<1><<<2048, 256, 0, stream>>>(x32, ew_csr, src_csr, rowptr, ginW, ginB,
                                          xh32, bnacc);
    k_bnfin<<<1, 64, 0, stream>>>(1, bng, bnb, bnacc, bnsc);
    k_bnapply<1><<<2048, 256, 0, stream>>>(bnsc, xh32, x32, out);
    k_att1<<<1024, 256, 0, stream>>>(x32, c64, sc, bmax);
    k_att2<<<16, 64, 0, stream>>>(bmax, mxg, num, den);
    k_att3<<<1024, 256, 0, stream>>>(x32, sc, mxg, num, den);
    k_att4<<<16, 64, 0, stream>>>(num, den, c64);

    // ---------------- heads + centroid output ----------------
    k_head<<<2048, 256, 0, stream>>>(x32, c64, hW1, hb1, hW2, hb2, out);
}

// Round 16
// 858.632 us; speedup vs baseline: 1.1360x; 1.1360x over previous
//
#include <hip/hip_runtime.h>
#include <hip/hip_bf16.h>

// GraphCAD forward on MI355X. All float I/O is f32.
// R22->R23: R22's shfl butterfly regressed (64 cross-lane ops/tile > sred
// cost); k_edge reverted to R21's shape (sred + 3 barriers, stride-64 LDS,
// 963.9us best). New lever: packed f32 VALU. (1) k_edge GEMM accumulates in
// f32x2 (acc2[4][2] += {av,av}*{w01}) so LLVM can select v_pk_fma_f32 -> GEMM
// issue halves; bit-exact (packed = two IEEE FMAs). (2) k_nodeup gather FMAs
// + GIN matvec move f64->f32 (2cyc, packable; rowbuf LDS halves); BN stats
// still f64-accumulated from f32 h. ~1e-7-class shift, same accepted class
// as R20's f32 k_P; FIXTH=2e-3/k_fix-f64 guard unchanged.

#define D 64
#define BSZ 16
#define NPG 4096
#define NN (BSZ * NPG)   // 65536 nodes
#define NE (NN * 16)     // 1048576 edges
#define NL 2
#define NTILE (NE / 64)  // 16384

#define FIXTH 2e-3f
#define FLAGCAP 65536

// output layout (elements, f32)
#define OUT_X  0u
#define OUT_EW 4194304u
#define OUT_C  5242880u
#define OUT_XL 5243904u
#define OUT_CL 9438208u
#define OUT_PA 9439232u

typedef __attribute__((ext_vector_type(2))) float f32x2;

__device__ __forceinline__ void atomAdd64(double* p, double v) { unsafeAtomicAdd(p, v); }

// ================= CSR build (dst is a static input; rebuilt per call) ======
__global__ __launch_bounds__(256) void k_deg(const int* __restrict__ edst,
                                             int* __restrict__ cnt) {
    int stride = gridDim.x * 256;
    for (int e = blockIdx.x * 256 + threadIdx.x; e < NE; e += stride)
        atomicAdd(&cnt[edst[e]], 1);
}

__global__ __launch_bounds__(256) void k_scan1(const int* __restrict__ cnt,
                                               int* __restrict__ rowptr,
                                               int* __restrict__ bsum) {
    __shared__ int sd[256];
    const int b = blockIdx.x, t = threadIdx.x;
    const int v = cnt[b * 256 + t];
    sd[t] = v;
    __syncthreads();
    for (int off = 1; off < 256; off <<= 1) {
        int tmp = (t >= off) ? sd[t - off] : 0;
        __syncthreads();
        sd[t] += tmp;
        __syncthreads();
    }
    rowptr[b * 256 + t] = sd[t] - v;  // exclusive
    if (t == 255) bsum[b] = sd[255];
}

__global__ __launch_bounds__(256) void k_scan2(int* __restrict__ bsum) {
    __shared__ int sd[256];
    const int t = threadIdx.x;
    const int v = bsum[t];
    sd[t] = v;
    __syncthreads();
    for (int off = 1; off < 256; off <<= 1) {
        int tmp = (t >= off) ? sd[t - off] : 0;
        __syncthreads();
        sd[t] += tmp;
        __syncthreads();
    }
    bsum[t] = sd[t] - v;  // exclusive
}

__global__ __launch_bounds__(256) void k_scan3(const int* __restrict__ bsum,
                                               int* __restrict__ rowptr,
                                               int* __restrict__ cursor) {
    const int i = blockIdx.x * 256 + threadIdx.x;
    const int r = rowptr[i] + bsum[blockIdx.x];
    rowptr[i] = r;
    cursor[i] = r;
    if (i == 0) rowptr[NN] = NE;
}

// fill CSR: slot -> original edge (eord), src (src_csr), dst (dst_csr).
__global__ __launch_bounds__(256) void k_fill(const int* __restrict__ esrc,
                                              const int* __restrict__ edst,
                                              int* __restrict__ cursor,
                                              int* __restrict__ eord,
                                              int* __restrict__ src_csr,
                                              int* __restrict__ dst_csr) {
    int stride = gridDim.x * 256;
    for (int e = blockIdx.x * 256 + threadIdx.x; e < NE; e += stride) {
        const int d = edst[e];
        int pos = atomicAdd(&cursor[d], 1);
        eord[pos] = e;
        src_csr[pos] = esrc[e];
        dst_csr[pos] = d;
    }
}

// ---- initial centroid: per-graph mean of x (f32 in, f64 out), 8 blocks/graph
__global__ __launch_bounds__(256) void k_centroid0(const float* __restrict__ xin,
                                                   double* __restrict__ c64) {
    const int g = blockIdx.x >> 3, sub = blockIdx.x & 7, tid = threadIdx.x;
    const int r = tid >> 6, f = tid & 63;
    __shared__ double cr[4][D];
    double s = 0.0;
    for (int k = 0; k < NPG / 8 / 4; ++k) {
        size_t n = (size_t)g * NPG + (size_t)(sub * (NPG / 8) + 4 * k + r);
        s += (double)xin[n * D + f];
    }
    cr[r][f] = s;
    __syncthreads();
    if (tid < D)
        atomAdd64(&c64[g * D + tid],
                  (cr[0][tid] + cr[1][tid] + cr[2][tid] + cr[3][tid]) * (1.0 / NPG));
}

// ---- qb = c @ W1b, qc = c @ W1c (per graph, f64) ----
__global__ __launch_bounds__(256) void k_qbc(const double* __restrict__ c64,
                                             const float* __restrict__ epW1,
                                             double* __restrict__ qb, double* __restrict__ qc) {
    int gj = blockIdx.x * 256 + threadIdx.x;
    if (gj >= BSZ * D) return;
    int g = gj >> 6, j = gj & 63;
    double sb = 0.0, sc = 0.0;
#pragma unroll
    for (int i = 0; i < D; ++i) {
        double cv = c64[g * D + i];
        sb += cv * (double)epW1[(D + i) * D + j];
        sc += cv * (double)epW1[(2 * D + i) * D + j];
    }
    qb[gj] = sb;
    qc[gj] = sc;
}

// ---- P'_b = x@W1b - qb[g], P'_c = x@W1c - qc[g]; f32 compute/store ----
template <int LAYER>
__global__ __launch_bounds__(256) void k_P(const float* __restrict__ xin,
                                           const float* __restrict__ x32,
                                           const float* __restrict__ epW1,
                                           const double* __restrict__ qb,
                                           const double* __restrict__ qc,
                                           float* __restrict__ Pb, float* __restrict__ Pc,
                                           double* __restrict__ bnacc) {
    if (blockIdx.x == 0 && threadIdx.x < 128) bnacc[threadIdx.x] = 0.0;
    __shared__ float wb[D * D];
    __shared__ float wc[D * D];
    __shared__ float xrow[4][D];
    int tid = threadIdx.x, w = tid >> 6, j = tid & 63;
    for (int idx = tid; idx < D * D; idx += 256) {
        int i = idx >> 6, c = idx & 63;
        wb[idx] = epW1[(D + i) * D + c];
        wc[idx] = epW1[(2 * D + i) * D + c];
    }
    __syncthreads();
    for (int grp = blockIdx.x; grp < NN / 4; grp += gridDim.x) {
        size_t n = (size_t)grp * 4 + w;
        xrow[w][j] = (LAYER == 0) ? xin[n * D + j] : x32[n * D + j];
        __syncthreads();
        float pb = 0.0f, pc = 0.0f;
#pragma unroll
        for (int i = 0; i < D; ++i) {
            const float xv = xrow[w][i];
            pb += xv * wb[i * D + j];
            pc += xv * wc[i * D + j];
        }
        const int g = (int)(n >> 12);
        Pb[n * D + j] = pb - (float)qb[g * D + j];
        Pc[n * D + j] = pc - (float)qc[g * D + j];
        __syncthreads();
    }
}

// ---- edge scorer, CSR order: all-f32 tile GEMM (packed f32x2 acc) ----
// Near-threshold edges (|score+g| < FIXTH) deferred to k_fix (f64).
// LDS: A f32 [64][64] (reused as sred, stride 17), W f32 [64][64] = 32768B.
template <int LAYER>
__global__ __launch_bounds__(256, 4) void k_edge(const float* __restrict__ xsrc,
                                                 const int* __restrict__ src_csr,
                                                 const int* __restrict__ dst_csr,
                                                 const int* __restrict__ eord,
                                                 const float* __restrict__ ewin,
                                                 float* __restrict__ ew_csr,
                                                 const float* __restrict__ unoise,
                                                 const float* __restrict__ epW1,
                                                 const float* __restrict__ epb1,
                                                 const float* __restrict__ epW2,
                                                 const float* __restrict__ epb2,
                                                 const float* __restrict__ alphap,
                                                 const float* __restrict__ Pb32,
                                                 const float* __restrict__ Pc32,
                                                 int* __restrict__ flagcnt,
                                                 int* __restrict__ flaglist,
                                                 float* __restrict__ out) {
    const int t = threadIdx.x;
    const int tx = t & 15, ty = t >> 4;

    __shared__ __align__(16) float ldsA[64 * 64];  // |dx| [dim][slot]
    __shared__ __align__(16) float ldsW[64 * 64];  // W1a [k][j]

    for (int idx = t; idx < D * D; idx += 256) {
        ldsW[idx] = epW1[idx];  // [k][j] layout matches epW1 row-major
    }
    float b1f[4], w2f[4];
#pragma unroll
    for (int c = 0; c < 4; ++c) {
        b1f[c] = epb1[4 * tx + c];
        w2f[c] = epW2[4 * tx + c];
    }
    const float b2v = epb2[0];
    const float alpha = alphap[0];
    __syncthreads();

    const int eloc = t >> 2, q = t & 3;

    for (int tile = blockIdx.x; tile < NTILE; tile += gridDim.x) {
        const int base = tile * 64;

        // ---- stage |x_d - x_s| (f32, transposed). d-rows run-repeat (L1). --
        {
            const int pos = base + eloc;
            const int s = src_csr[pos], d = dst_csr[pos];
            const float* rs = xsrc + (size_t)s * D + q * 16;
            const float* rd = xsrc + (size_t)d * D + q * 16;
#pragma unroll
            for (int c = 0; c < 4; ++c) {
                const float4 fd = *(const float4*)(rd + 4 * c);
                const float4 fs = *(const float4*)(rs + 4 * c);
                const int dim = q * 16 + 4 * c;
                ldsA[(dim + 0) * 64 + eloc] = fabsf(fd.x - fs.x);
                ldsA[(dim + 1) * 64 + eloc] = fabsf(fd.y - fs.y);
                ldsA[(dim + 2) * 64 + eloc] = fabsf(fd.z - fs.z);
                ldsA[(dim + 3) * 64 + eloc] = fabsf(fd.w - fs.w);
            }
        }
        __syncthreads();

        // ---- 64x64x64 GEMM: f32 inputs, packed f32x2 accumulate ----
        f32x2 acc2[4][2];
#pragma unroll
        for (int r = 0; r < 4; ++r)
#pragma unroll
            for (int c = 0; c < 2; ++c) {
                f32x2 z = {0.0f, 0.0f};
                acc2[r][c] = z;
            }

#pragma unroll 4
        for (int k = 0; k < 64; ++k) {
            const float4 af = *(const float4*)&ldsA[k * 64 + 4 * ty];
            const float4 wf = *(const float4*)&ldsW[k * 64 + 4 * tx];
            const f32x2 w01 = {wf.x, wf.y};
            const f32x2 w23 = {wf.z, wf.w};
            const float av[4] = {af.x, af.y, af.z, af.w};
#pragma unroll
            for (int r = 0; r < 4; ++r) {
                const f32x2 avv = {av[r], av[r]};
                acc2[r][0] += avv * w01;  // -> v_pk_fma_f32
                acc2[r][1] += avv * w23;
            }
        }
        __syncthreads();  // A dead -> reuse as f32 sred

        float* sred = ldsA;
        // ---- epilogue: + P' terms, +b1, relu, * w2, partial sums ----
#pragma unroll
        for (int r = 0; r < 4; ++r) {
            const int pos = base + 4 * ty + r;
            const int s = src_csr[pos], d = dst_csr[pos];
            const float4 pb = *(const float4*)(Pb32 + (size_t)d * D + 4 * tx);
            const float4 pc = *(const float4*)(Pc32 + (size_t)s * D + 4 * tx);
            float part = 0.0f;
            float h;
            h = acc2[r][0].x + pb.x + pc.x + b1f[0];
            if (h > 0.0f) part += h * w2f[0];
            h = acc2[r][0].y + pb.y + pc.y + b1f[1];
            if (h > 0.0f) part += h * w2f[1];
            h = acc2[r][1].x + pb.z + pc.z + b1f[2];
            if (h > 0.0f) part += h * w2f[2];
            h = acc2[r][1].y + pb.w + pc.w + b1f[3];
            if (h > 0.0f) part += h * w2f[3];
            sred[(4 * ty + r) * 17 + tx] = part;
        }
        __syncthreads();

        // ---- score reduce + RelaxedBernoulli sample (one lane per slot) ----
        if (t < 64) {
            float sc_ = b2v;
#pragma unroll
            for (int i = 0; i < 16; ++i) sc_ += sred[t * 17 + i];
            const int pos = base + t;
            const int e = eord[pos];
            const float u = unoise[(size_t)LAYER * NE + e];
            const float gn = logf(u) - log1pf(-u);
            const float mar = sc_ + gn;  // decision margin; samp == (mar > 0)
            bool deferred = false;
            if (fabsf(mar) < FIXTH) {
                int slot = atomicAdd(flagcnt, 1);
                if (slot < FLAGCAP) {
                    flaglist[slot] = pos;
                    deferred = true;  // k_fix decides + writes this edge
                }
            }
            if (!deferred) {
                const float pre = 1.0f / (1.0f + expf(-sc_));
                const bool samp = mar > 0.0f;
                const float ewo = (LAYER == 0) ? ewin[e] : ew_csr[pos];
                const float ewn = samp ? alpha * ewo + (1.0f - alpha) * pre : 0.0f;
                ew_csr[pos] = ewn;
                if (LAYER == NL - 1) {
                    out[OUT_EW + (size_t)e] = ewn;
                    out[OUT_PA + (size_t)e] = pre;
                }
            }
        }
        __syncthreads();
    }
}

// ---- exact f64 re-decision for near-threshold edges (one wave per edge) ----
template <int LAYER>
__global__ __launch_bounds__(256) void k_fix(const float* __restrict__ xsrc,
                                             const int* __restrict__ src_csr,
                                             const int* __restrict__ dst_csr,
                                             const int* __restrict__ eord,
                                             const float* __restrict__ ewin,
                                             float* __restrict__ ew_csr,
                                             const float* __restrict__ unoise,
                                             const float* __restrict__ epW1,
                                             const float* __restrict__ epb1,
                                             const float* __restrict__ epW2,
                                             const float* __restrict__ epb2,
                                             const float* __restrict__ alphap,
                                             const float* __restrict__ Pb32,
                                             const float* __restrict__ Pc32,
                                             const int* __restrict__ flagcnt,
                                             const int* __restrict__ flaglist,
                                             float* __restrict__ out) {
    const int n = min(flagcnt[0], FLAGCAP);
    __shared__ float dxs[4][D];
    const int w = threadIdx.x >> 6, lane = threadIdx.x & 63;
    const int nw = gridDim.x * 4;
    for (int i = blockIdx.x * 4 + w; i < n; i += nw) {
        const int pos = flaglist[i];
        const int s = src_csr[pos], d = dst_csr[pos];
        // |dx| from the same f32 inputs the main kernel staged
        dxs[w][lane] = fabsf(xsrc[(size_t)d * D + lane] - xsrc[(size_t)s * D + lane]);
        // wave-internal broadcast (same-wave DS in-order)
        double h = 0.0;
#pragma unroll
        for (int k = 0; k < D; ++k) h += (double)dxs[w][k] * (double)epW1[k * D + lane];
        h += (double)Pb32[(size_t)d * D + lane] + (double)Pc32[(size_t)s * D + lane] +
             (double)epb1[lane];
        double part = (h > 0.0) ? h * (double)epW2[lane] : 0.0;
#pragma unroll
        for (int off = 32; off; off >>= 1) part += __shfl_xor(part, off);
        if (lane == 0) {
            const double sc_ = part + (double)epb2[0];
            const int e = eord[pos];
            const double u = (double)unoise[(size_t)LAYER * NE + e];
            const double gn = log(u) - log1p(-u);
            const double pre = 1.0 / (1.0 + exp(-sc_));
            const bool samp = (sc_ + gn) > 0.0;
            const double ewo = (LAYER == 0) ? (double)ewin[e] : (double)ew_csr[pos];
            const double alpha = (double)alphap[0];
            const double ewn = samp ? alpha * ewo + (1.0 - alpha) * pre : 0.0;
            ew_csr[pos] = (float)ewn;
            if (LAYER == NL - 1) {
                out[OUT_EW + (size_t)e] = (float)ewn;
                out[OUT_PA + (size_t)e] = (float)pre;
            }
        }
    }
}

// ---- node update: CSR gather (row-parallel loads) + GIN mlp + BN partials --
// Lane = (slot e=0..3, quarter q=0..15). All arithmetic f32 (packable);
// BN stats s1/s2 accumulated in f64 from the f32 h.
template <int LAYER>
__global__ __launch_bounds__(256) void k_nodeup(const float* __restrict__ xsrc,
                                                const float* __restrict__ ew_csr,
                                                const int* __restrict__ src_csr,
                                                const int* __restrict__ rowptr,
                                                const float* __restrict__ ginW,
                                                const float* __restrict__ ginB,
                                                float* __restrict__ xh,
                                                double* __restrict__ bnacc) {
    __shared__ float wg[D * D];
    __shared__ float rowbuf[4][D];
    __shared__ double bn1[4][D];
    __shared__ double bn2[4][D];
    const int t = threadIdx.x, w = t >> 6, lane = t & 63;
    const int e = lane >> 4, q = lane & 15;  // slot, quarter (dims 4q..4q+3)
    for (int idx = t; idx < D * D; idx += 256) wg[idx] = ginW[LAYER * D * D + idx];
    const float bj = ginB[LAYER * D + lane];
    __syncthreads();
    double s1 = 0.0, s2 = 0.0;
    const int nwaves = gridDim.x * 4;
    for (int n = blockIdx.x * 4 + w; n < NN; n += nwaves) {
        const int rs = rowptr[n], re = rowptr[n + 1];
        const int deg = re - rs;
        // ---- first 16 edges: 4 masked slots x 4 chunks, all loads up front
        const int i0 = rs + ((e < deg) ? e : 0);
        const int i1 = rs + ((4 + e < deg) ? 4 + e : 0);
        const int i2 = rs + ((8 + e < deg) ? 8 + e : 0);
        const int i3 = rs + ((12 + e < deg) ? 12 + e : 0);
        const float w0 = (e < deg) ? ew_csr[i0] : 0.f;
        const float w1 = (4 + e < deg) ? ew_csr[i1] : 0.f;
        const float w2 = (8 + e < deg) ? ew_csr[i2] : 0.f;
        const float w3 = (12 + e < deg) ? ew_csr[i3] : 0.f;
        const int s0 = src_csr[i0], s1_ = src_csr[i1];
        const int s2_ = src_csr[i2], s3_ = src_csr[i3];
        const float4 r0 = *(const float4*)(xsrc + (size_t)s0 * D + 4 * q);
        const float4 r1 = *(const float4*)(xsrc + (size_t)s1_ * D + 4 * q);
        const float4 r2 = *(const float4*)(xsrc + (size_t)s2_ * D + 4 * q);
        const float4 r3 = *(const float4*)(xsrc + (size_t)s3_ * D + 4 * q);
        const float4 rf = *(const float4*)(xsrc + (size_t)n * D + 4 * q);  // self
        float a0 = w0 * r0.x, a1 = w0 * r0.y, a2 = w0 * r0.z, a3 = w0 * r0.w;
        a0 += w1 * r1.x;
        a1 += w1 * r1.y;
        a2 += w1 * r1.z;
        a3 += w1 * r1.w;
        a0 += w2 * r2.x;
        a1 += w2 * r2.y;
        a2 += w2 * r2.z;
        a3 += w2 * r2.w;
        a0 += w3 * r3.x;
        a1 += w3 * r3.y;
        a2 += w3 * r3.z;
        a3 += w3 * r3.w;
        // ---- tail: edges beyond 16, masked chunks of 4 (wave-uniform bound)
        for (int k = rs + 16; k < re; k += 4) {
            const int kk = k + e;
            const bool v = kk < re;
            const float wt = v ? ew_csr[kk] : 0.f;
            const int st = src_csr[v ? kk : rs];
            const float4 rt = *(const float4*)(xsrc + (size_t)st * D + 4 * q);
            a0 += wt * rt.x;
            a1 += wt * rt.y;
            a2 += wt * rt.z;
            a3 += wt * rt.w;
        }
        // ---- tree-reduce the 4 slots (lanes differing in bits 4,5) ----
        a0 += __shfl_xor(a0, 16);
        a1 += __shfl_xor(a1, 16);
        a2 += __shfl_xor(a2, 16);
        a3 += __shfl_xor(a3, 16);
        a0 += __shfl_xor(a0, 32);
        a1 += __shfl_xor(a1, 32);
        a2 += __shfl_xor(a2, 32);
        a3 += __shfl_xor(a3, 32);
        // ---- + self, publish to rowbuf (same-wave DS in-order) ----
        if (e == 0) {
            rowbuf[w][4 * q + 0] = a0 + rf.x;
            rowbuf[w][4 * q + 1] = a1 + rf.y;
            rowbuf[w][4 * q + 2] = a2 + rf.z;
            rowbuf[w][4 * q + 3] = a3 + rf.w;
        }
        // ---- GIN matvec (f32) ----
        float h = bj;
#pragma unroll
        for (int i = 0; i < D; ++i) h += rowbuf[w][i] * wg[i * D + lane];
        h = h > 0.0f ? h : 0.0f;
        xh[(size_t)n * D + lane] = h;
        s1 += (double)h;
        s2 += (double)h * (double)h;
    }
    // ---- block-level reduce, then 2 atomics per lane-column per block ----
    bn1[w][lane] = s1;
    bn2[w][lane] = s2;
    __syncthreads();
    if (w == 0) {
        atomAdd64(&bnacc[lane], bn1[0][lane] + bn1[1][lane] + bn1[2][lane] + bn1[3][lane]);
        atomAdd64(&bnacc[64 + lane], bn2[0][lane] + bn2[1][lane] + bn2[2][lane] + bn2[3][lane]);
    }
}

// ---- BN finalize ----
__global__ __launch_bounds__(64) void k_bnfin(int layer, const float* __restrict__ gamma,
                                              const float* __restrict__ beta,
                                              const double* __restrict__ bnacc,
                                              double* __restrict__ bnsc) {
    int j = threadIdx.x;
    double mu = bnacc[j] * (1.0 / NN);
    double var = bnacc[64 + j] * (1.0 / NN) - mu * mu;
    double sc = (double)gamma[layer * D + j] / sqrt(var + 1e-5);
    bnsc[j] = sc;
    bnsc[64 + j] = (double)beta[layer * D + j] - mu * sc;
}

// ---- BN apply -> x32 (f64 affine, single rounding; final out at layer 1) --
template <int LAYER>
__global__ __launch_bounds__(256) void k_bnapply(const double* __restrict__ bnsc,
                                                 const float* __restrict__ xh,
                                                 float* __restrict__ x32,
                                                 float* __restrict__ out) {
    size_t stride = (size_t)gridDim.x * 256;
    for (size_t i = (size_t)blockIdx.x * 256 + threadIdx.x; i < (size_t)NN * D; i += stride) {
        int j = (int)(i & 63);
        const float v = (float)(bnsc[j] * (double)xh[i] + bnsc[64 + j]);
        x32[i] = v;
        if (LAYER == NL - 1) out[OUT_X + i] = v;
    }
}

// ---- attention pooling, parallelized: 4 kernels (x in f32, math f64) ----
__global__ __launch_bounds__(256) void k_att1(const float* __restrict__ x32,
                                              const double* __restrict__ c64,
                                              double* __restrict__ sc,
                                              double* __restrict__ bmax) {
    const int blk = blockIdx.x, t = threadIdx.x, w = t >> 6, lane = t & 63;
    const int g = blk >> 6;
    __shared__ double wmax[4];
    const double cj = c64[g * D + lane];
    double locmax = -1e300;
    for (int m = 0; m < 16; ++m) {
        const int n = blk * 64 + w * 16 + m;
        double v = (double)x32[(size_t)n * D + lane] * cj;
#pragma unroll
        for (int off = 32; off; off >>= 1) v += __shfl_xor(v, off);
        if (lane == 0) sc[n] = v;
        locmax = fmax(locmax, v);
    }
    if (lane == 0) wmax[w] = locmax;
    __syncthreads();
    if (t == 0) bmax[blk] = fmax(fmax(wmax[0], wmax[1]), fmax(wmax[2], wmax[3]));
}

__global__ __launch_bounds__(64) void k_att2(const double* __restrict__ bmax,
                                             double* __restrict__ mxg,
                                             double* __restrict__ num,
                                             double* __restrict__ den) {
    const int g = blockIdx.x, t = threadIdx.x;
    double m = bmax[g * 64 + t];
#pragma unroll
    for (int off = 32; off; off >>= 1) m = fmax(m, __shfl_xor(m, off));
    if (t == 0) {
        mxg[g] = m;
        den[g] = 0.0;
    }
    num[g * D + t] = 0.0;
}

__global__ __launch_bounds__(256) void k_att3(const float* __restrict__ x32,
                                              const double* __restrict__ sc,
                                              const double* __restrict__ mxg,
                                              double* __restrict__ num,
                                              double* __restrict__ den) {
    const int blk = blockIdx.x, t = threadIdx.x, w = t >> 6, lane = t & 63;
    const int g = blk >> 6;
    __shared__ double cp[4][D];
    __shared__ double wes[4];
    const double mx = mxg[g];
    double accj = 0.0, esum = 0.0;
    for (int m = 0; m < 16; ++m) {
        const int n = blk * 64 + w * 16 + m;
        const double e = exp(sc[n] - mx);
        accj += e * (double)x32[(size_t)n * D + lane];
        esum += e;
    }
    cp[w][lane] = accj;
    if (lane == 0) wes[w] = esum;
    __syncthreads();
    if (t < D) {
        atomAdd64(&num[g * D + t], cp[0][t] + cp[1][t] + cp[2][t] + cp[3][t]);
        if (t == 0) atomAdd64(&den[g], wes[0] + wes[1] + wes[2] + wes[3]);
    }
}

__global__ __launch_bounds__(64) void k_att4(const double* __restrict__ num,
                                             const double* __restrict__ den,
                                             double* __restrict__ c64) {
    const int g = blockIdx.x, t = threadIdx.x;
    c64[g * D + t] = num[g * D + t] / den[g];
}

// ---- head: relu(x@W1+b1)@W2+b2 for all nodes + 16 centroid rows (f32) ----
__global__ __launch_bounds__(256) void k_head(const float* __restrict__ x32,
                                              const double* __restrict__ c64,
                                              const float* __restrict__ hW1,
                                              const float* __restrict__ hb1,
                                              const float* __restrict__ hW2,
                                              const float* __restrict__ hb2,
                                              float* __restrict__ out) {
    __shared__ float w1[D * D];
    __shared__ float w2[D * D];
    __shared__ float xr[4][D];
    __shared__ float hr[4][D];
    int tid = threadIdx.x, w = tid >> 6, j = tid & 63;
    for (int idx = tid; idx < D * D; idx += 256) {
        w1[idx] = hW1[idx];
        w2[idx] = hW2[idx];
    }
    const float b1j = hb1[j];
    const float b2j = hb2[j];
    __syncthreads();
    const int ROWS = NN + BSZ;
    for (int grp = blockIdx.x; grp * 4 < ROWS; grp += gridDim.x) {
        int r = grp * 4 + w;
        bool valid = r < ROWS;
        float xv = 0.f;
        if (valid)
            xv = (r < NN) ? x32[(size_t)r * D + j] : (float)c64[(size_t)(r - NN) * D + j];
        xr[w][j] = xv;
        __syncthreads();
        if (valid) {
            float h = b1j;
#pragma unroll
            for (int i = 0; i < D; ++i) h += xr[w][i] * w1[i * D + j];
            hr[w][j] = h > 0.f ? h : 0.f;
        }
        __syncthreads();
        if (valid) {
            float o = b2j;
#pragma unroll
            for (int i = 0; i < D; ++i) o += hr[w][i] * w2[i * D + j];
            if (r < NN) {
                out[OUT_XL + (size_t)r * D + j] = o;
            } else {
                size_t cr = (size_t)(r - NN) * D + j;
                out[OUT_CL + cr] = o;
                out[OUT_C + cr] = (float)c64[cr];
            }
        }
        __syncthreads();
    }
}

extern "C" void kernel_launch(void* const* d_in, const int* in_sizes, int n_in,
                              void* d_out, int out_size, void* d_ws, size_t ws_size,
                              hipStream_t stream) {
    const float* xin    = (const float*)d_in[0];
    const int*   ei     = (const int*)d_in[1];
    const float* ewin   = (const float*)d_in[2];
    const float* unoise = (const float*)d_in[5];
    const float* epW1   = (const float*)d_in[6];
    const float* epb1   = (const float*)d_in[7];
    const float* epW2   = (const float*)d_in[8];
    const float* epb2   = (const float*)d_in[9];
    const float* alphap = (const float*)d_in[10];
    const float* ginW   = (const float*)d_in[11];
    const float* ginB   = (const float*)d_in[12];
    const float* bng    = (const float*)d_in[13];
    const float* bnb    = (const float*)d_in[14];
    const float* hW1    = (const float*)d_in[15];
    const float* hb1    = (const float*)d_in[16];
    const float* hW2    = (const float*)d_in[17];
    const float* hb2    = (const float*)d_in[18];
    float* out = (float*)d_out;
    const int* esrc = ei;
    const int* edst = ei + NE;

    char* ws = (char*)d_ws;
    const size_t SZ4 = (size_t)NN * D * sizeof(float);  // 16MB
    // Pb (k_P->k_edge/k_fix) and xh (k_nodeup->k_bnapply): disjoint live ranges.
    float* Pb32 = (float*)(ws);
    float* xh32 = Pb32;  // alias
    float* Pc32 = (float*)(ws + SZ4);
    float* x32  = (float*)(ws + 2 * SZ4);
    float* ew_csr = (float*)(ws + 3 * SZ4);                       // NE*4 = 4MB
    double* sc  = (double*)(ws + 3 * SZ4 + (size_t)NE * 4);       // NN*8
    char*  p    = ws + 3 * SZ4 + (size_t)NE * 4 + (size_t)NN * 8;
    double* c64  = (double*)p;          p += BSZ * D * 8;
    double* qb   = (double*)p;          p += BSZ * D * 8;
    double* qc   = (double*)p;          p += BSZ * D * 8;
    double* bnacc = (double*)p;         p += 128 * 8;
    double* bnsc  = (double*)p;         p += 128 * 8;
    double* bmax  = (double*)p;         p += 1024 * 8;
    double* mxg   = (double*)p;         p += 16 * 8;
    double* num   = (double*)p;         p += BSZ * D * 8;
    double* den   = (double*)p;         p += 16 * 8;
    // CSR
    int* cnt     = (int*)p;             p += (size_t)NN * 4;
    int* rowptr  = (int*)p;             p += (size_t)(NN + 1) * 4 + 4;
    int* cursor  = (int*)p;             p += (size_t)NN * 4;
    int* bsum    = (int*)p;             p += 256 * 4;
    int* eord    = (int*)p;             p += (size_t)NE * 4;
    int* src_csr = (int*)p;             p += (size_t)NE * 4;
    int* dst_csr = (int*)p;             p += (size_t)NE * 4;
    // near-threshold fixup list
    int* flagcnt  = (int*)p;            p += 8;
    int* flaglist = (int*)p;            p += (size_t)FLAGCAP * 4;

    // ---- CSR build (dst static) ----
    hipMemsetAsync(cnt, 0, (size_t)NN * 4, stream);
    k_deg<<<1024, 256, 0, stream>>>(edst, cnt);
    k_scan1<<<256, 256, 0, stream>>>(cnt, rowptr, bsum);
    k_scan2<<<1, 256, 0, stream>>>(bsum);
    k_scan3<<<256, 256, 0, stream>>>(bsum, rowptr, cursor);
    k_fill<<<1024, 256, 0, stream>>>(esrc, edst, cursor, eord, src_csr, dst_csr);

    hipMemsetAsync(c64, 0, (size_t)BSZ * D * 8, stream);
    k_centroid0<<<BSZ * 8, 256, 0, stream>>>(xin, c64);

    // ---------------- layer 0 ----------------
    k_qbc<<<4, 256, 0, stream>>>(c64, epW1, qb, qc);
    k_P<0><<<2048, 256, 0, stream>>>(xin, x32, epW1, qb, qc, Pb32, Pc32, bnacc);
    hipMemsetAsync(flagcnt, 0, 4, stream);
    k_edge<0><<<2048, 256, 0, stream>>>(xin, src_csr, dst_csr, eord, ewin, ew_csr, unoise,
                                        epW1, epb1, epW2, epb2, alphap, Pb32, Pc32,
                                        flagcnt, flaglist, out);
    k_fix<0><<<64, 256, 0, stream>>>(xin, src_csr, dst_csr, eord, ewin, ew_csr, unoise,
                                     epW1, epb1, epW2, epb2, alphap, Pb32, Pc32,
                                     flagcnt, flaglist, out);
    k_nodeup<0><<<2048, 256, 0, stream>>>(xin, ew_csr, src_csr, rowptr, ginW, ginB,
                                          xh32, bnacc);
    k_bnfin<<<1, 64, 0, stream>>>(0, bng, bnb, bnacc, bnsc);
    k_bnapply<0><<<2048, 256, 0, stream>>>(bnsc, xh32, x32, out);
    k_att1<<<1024, 256, 0, stream>>>(x32, c64, sc, bmax);
    k_att2<<<16, 64, 0, stream>>>(bmax, mxg, num, den);
    k_att3<<<1024, 256, 0, stream>>>(x32, sc, mxg, num, den);
    k_att4<<<16, 64, 0, stream>>>(num, den, c64);

    // ---------------- layer 1 ----------------
    k_qbc<<<4, 256, 0, stream>>>(c64, epW1, qb, qc);
    k_P<1><<<2048, 256, 0, stream>>>(xin, x32, epW1, qb, qc, Pb32, Pc32, bnacc);
    hipMemsetAsync(flagcnt, 0, 4, stream);
    k_edge<1><<<2048, 256, 0, stream>>>(x32, src_csr, dst_csr, eord, ewin, ew_csr, unoise,
                                        epW1, epb1, epW2, epb2, alphap, Pb32, Pc32,
                                        flagcnt, flaglist, out);
    k_fix<1><<<64, 256, 0, stream>>>(x32, src_csr, dst_csr, eord, ewin, ew_csr, unoise,
                                     epW1, epb1, epW2, epb2, alphap, Pb32, Pc32,
                                     flagcnt, flaglist, out);
    k_nodeup<1><<<2048, 256, 0, stream>>>(x32, ew_csr, src_csr, rowptr, ginW, ginB,
                                          xh32, bnacc);
    k_bnfin<<<1, 64, 0, stream>>>(1, bng, bnb, bnacc, bnsc);
    k_bnapply<1><<<2048, 256, 0, stream>>>(bnsc, xh32, x32, out);
    k_att1<<<1024, 256, 0, stream>>>(x32, c64, sc, bmax);
    k_att2<<<16, 64, 0, stream>>>(bmax, mxg, num, den);
    k_att3<<<1024, 256, 0, stream>>>(x32, sc, mxg, num, den);
    k_att4<<<16, 64, 0, stream>>>(num, den, c64);

    // ---------------- heads + centroid output ----------------
    k_head<<<2048, 256, 0, stream>>>(x32, c64, hW1, hb1, hW2, hb2, out);
}

// Round 17
// 846.305 us; speedup vs baseline: 1.1526x; 1.0146x over previous
//
#include <hip/hip_runtime.h>
#include <hip/hip_bf16.h>

// GraphCAD forward on MI355X. All float I/O is f32.
// R23->R24: R23 proved k_nodeup is ISSUE-bound (f64->f32 => -105us). Shave
// its issue count further: (1) GIN weights transposed in LDS (wgT[64][65],
// stride-65 -> 2-way/free) so the matvec reads 16 ds_read_b128 instead of
// 64 scalar reads; (2) rowbuf read as 16 float4 broadcasts; (3) packed
// f32x2 FMAs in matvec (2 partial accs, ~1e-7 reorder) and gather (per-
// component order identical to R23 -> bit-same). And k_bnapply is FUSED
// into k_att1 (applies BN affine from xh/bnsc, writes x32/out, scores from
// the identical rounded value) - bit-identical pipeline, deletes a 32MB
// pass/layer. k_edge (latency-floor, 177us) and all else unchanged.

#define D 64
#define BSZ 16
#define NPG 4096
#define NN (BSZ * NPG)   // 65536 nodes
#define NE (NN * 16)     // 1048576 edges
#define NL 2
#define NTILE (NE / 64)  // 16384

#define FIXTH 2e-3f
#define FLAGCAP 65536

// output layout (elements, f32)
#define OUT_X  0u
#define OUT_EW 4194304u
#define OUT_C  5242880u
#define OUT_XL 5243904u
#define OUT_CL 9438208u
#define OUT_PA 9439232u

typedef __attribute__((ext_vector_type(2))) float f32x2;

__device__ __forceinline__ void atomAdd64(double* p, double v) { unsafeAtomicAdd(p, v); }

// ================= CSR build (dst is a static input; rebuilt per call) ======
__global__ __launch_bounds__(256) void k_deg(const int* __restrict__ edst,
                                             int* __restrict__ cnt) {
    int stride = gridDim.x * 256;
    for (int e = blockIdx.x * 256 + threadIdx.x; e < NE; e += stride)
        atomicAdd(&cnt[edst[e]], 1);
}

__global__ __launch_bounds__(256) void k_scan1(const int* __restrict__ cnt,
                                               int* __restrict__ rowptr,
                                               int* __restrict__ bsum) {
    __shared__ int sd[256];
    const int b = blockIdx.x, t = threadIdx.x;
    const int v = cnt[b * 256 + t];
    sd[t] = v;
    __syncthreads();
    for (int off = 1; off < 256; off <<= 1) {
        int tmp = (t >= off) ? sd[t - off] : 0;
        __syncthreads();
        sd[t] += tmp;
        __syncthreads();
    }
    rowptr[b * 256 + t] = sd[t] - v;  // exclusive
    if (t == 255) bsum[b] = sd[255];
}

__global__ __launch_bounds__(256) void k_scan2(int* __restrict__ bsum) {
    __shared__ int sd[256];
    const int t = threadIdx.x;
    const int v = bsum[t];
    sd[t] = v;
    __syncthreads();
    for (int off = 1; off < 256; off <<= 1) {
        int tmp = (t >= off) ? sd[t - off] : 0;
        __syncthreads();
        sd[t] += tmp;
        __syncthreads();
    }
    bsum[t] = sd[t] - v;  // exclusive
}

__global__ __launch_bounds__(256) void k_scan3(const int* __restrict__ bsum,
                                               int* __restrict__ rowptr,
                                               int* __restrict__ cursor) {
    const int i = blockIdx.x * 256 + threadIdx.x;
    const int r = rowptr[i] + bsum[blockIdx.x];
    rowptr[i] = r;
    cursor[i] = r;
    if (i == 0) rowptr[NN] = NE;
}

// fill CSR: slot -> original edge (eord), src (src_csr), dst (dst_csr).
__global__ __launch_bounds__(256) void k_fill(const int* __restrict__ esrc,
                                              const int* __restrict__ edst,
                                              int* __restrict__ cursor,
                                              int* __restrict__ eord,
                                              int* __restrict__ src_csr,
                                              int* __restrict__ dst_csr) {
    int stride = gridDim.x * 256;
    for (int e = blockIdx.x * 256 + threadIdx.x; e < NE; e += stride) {
        const int d = edst[e];
        int pos = atomicAdd(&cursor[d], 1);
        eord[pos] = e;
        src_csr[pos] = esrc[e];
        dst_csr[pos] = d;
    }
}

// ---- initial centroid: per-graph mean of x (f32 in, f64 out), 8 blocks/graph
__global__ __launch_bounds__(256) void k_centroid0(const float* __restrict__ xin,
                                                   double* __restrict__ c64) {
    const int g = blockIdx.x >> 3, sub = blockIdx.x & 7, tid = threadIdx.x;
    const int r = tid >> 6, f = tid & 63;
    __shared__ double cr[4][D];
    double s = 0.0;
    for (int k = 0; k < NPG / 8 / 4; ++k) {
        size_t n = (size_t)g * NPG + (size_t)(sub * (NPG / 8) + 4 * k + r);
        s += (double)xin[n * D + f];
    }
    cr[r][f] = s;
    __syncthreads();
    if (tid < D)
        atomAdd64(&c64[g * D + tid],
                  (cr[0][tid] + cr[1][tid] + cr[2][tid] + cr[3][tid]) * (1.0 / NPG));
}

// ---- qb = c @ W1b, qc = c @ W1c (per graph, f64) ----
__global__ __launch_bounds__(256) void k_qbc(const double* __restrict__ c64,
                                             const float* __restrict__ epW1,
                                             double* __restrict__ qb, double* __restrict__ qc) {
    int gj = blockIdx.x * 256 + threadIdx.x;
    if (gj >= BSZ * D) return;
    int g = gj >> 6, j = gj & 63;
    double sb = 0.0, sc = 0.0;
#pragma unroll
    for (int i = 0; i < D; ++i) {
        double cv = c64[g * D + i];
        sb += cv * (double)epW1[(D + i) * D + j];
        sc += cv * (double)epW1[(2 * D + i) * D + j];
    }
    qb[gj] = sb;
    qc[gj] = sc;
}

// ---- P'_b = x@W1b - qb[g], P'_c = x@W1c - qc[g]; f32 compute/store ----
template <int LAYER>
__global__ __launch_bounds__(256) void k_P(const float* __restrict__ xin,
                                           const float* __restrict__ x32,
                                           const float* __restrict__ epW1,
                                           const double* __restrict__ qb,
                                           const double* __restrict__ qc,
                                           float* __restrict__ Pb, float* __restrict__ Pc,
                                           double* __restrict__ bnacc) {
    if (blockIdx.x == 0 && threadIdx.x < 128) bnacc[threadIdx.x] = 0.0;
    __shared__ float wb[D * D];
    __shared__ float wc[D * D];
    __shared__ float xrow[4][D];
    int tid = threadIdx.x, w = tid >> 6, j = tid & 63;
    for (int idx = tid; idx < D * D; idx += 256) {
        int i = idx >> 6, c = idx & 63;
        wb[idx] = epW1[(D + i) * D + c];
        wc[idx] = epW1[(2 * D + i) * D + c];
    }
    __syncthreads();
    for (int grp = blockIdx.x; grp < NN / 4; grp += gridDim.x) {
        size_t n = (size_t)grp * 4 + w;
        xrow[w][j] = (LAYER == 0) ? xin[n * D + j] : x32[n * D + j];
        __syncthreads();
        float pb = 0.0f, pc = 0.0f;
#pragma unroll
        for (int i = 0; i < D; ++i) {
            const float xv = xrow[w][i];
            pb += xv * wb[i * D + j];
            pc += xv * wc[i * D + j];
        }
        const int g = (int)(n >> 12);
        Pb[n * D + j] = pb - (float)qb[g * D + j];
        Pc[n * D + j] = pc - (float)qc[g * D + j];
        __syncthreads();
    }
}

// ---- edge scorer, CSR order: all-f32 tile GEMM (packed f32x2 acc) ----
// Near-threshold edges (|score+g| < FIXTH) deferred to k_fix (f64).
// LDS: A f32 [64][64] (reused as sred, stride 17), W f32 [64][64] = 32768B.
template <int LAYER>
__global__ __launch_bounds__(256, 4) void k_edge(const float* __restrict__ xsrc,
                                                 const int* __restrict__ src_csr,
                                                 const int* __restrict__ dst_csr,
                                                 const int* __restrict__ eord,
                                                 const float* __restrict__ ewin,
                                                 float* __restrict__ ew_csr,
                                                 const float* __restrict__ unoise,
                                                 const float* __restrict__ epW1,
                                                 const float* __restrict__ epb1,
                                                 const float* __restrict__ epW2,
                                                 const float* __restrict__ epb2,
                                                 const float* __restrict__ alphap,
                                                 const float* __restrict__ Pb32,
                                                 const float* __restrict__ Pc32,
                                                 int* __restrict__ flagcnt,
                                                 int* __restrict__ flaglist,
                                                 float* __restrict__ out) {
    const int t = threadIdx.x;
    const int tx = t & 15, ty = t >> 4;

    __shared__ __align__(16) float ldsA[64 * 64];  // |dx| [dim][slot]
    __shared__ __align__(16) float ldsW[64 * 64];  // W1a [k][j]

    for (int idx = t; idx < D * D; idx += 256) {
        ldsW[idx] = epW1[idx];  // [k][j] layout matches epW1 row-major
    }
    float b1f[4], w2f[4];
#pragma unroll
    for (int c = 0; c < 4; ++c) {
        b1f[c] = epb1[4 * tx + c];
        w2f[c] = epW2[4 * tx + c];
    }
    const float b2v = epb2[0];
    const float alpha = alphap[0];
    __syncthreads();

    const int eloc = t >> 2, q = t & 3;

    for (int tile = blockIdx.x; tile < NTILE; tile += gridDim.x) {
        const int base = tile * 64;

        // ---- stage |x_d - x_s| (f32, transposed). d-rows run-repeat (L1). --
        {
            const int pos = base + eloc;
            const int s = src_csr[pos], d = dst_csr[pos];
            const float* rs = xsrc + (size_t)s * D + q * 16;
            const float* rd = xsrc + (size_t)d * D + q * 16;
#pragma unroll
            for (int c = 0; c < 4; ++c) {
                const float4 fd = *(const float4*)(rd + 4 * c);
                const float4 fs = *(const float4*)(rs + 4 * c);
                const int dim = q * 16 + 4 * c;
                ldsA[(dim + 0) * 64 + eloc] = fabsf(fd.x - fs.x);
                ldsA[(dim + 1) * 64 + eloc] = fabsf(fd.y - fs.y);
                ldsA[(dim + 2) * 64 + eloc] = fabsf(fd.z - fs.z);
                ldsA[(dim + 3) * 64 + eloc] = fabsf(fd.w - fs.w);
            }
        }
        __syncthreads();

        // ---- 64x64x64 GEMM: f32 inputs, packed f32x2 accumulate ----
        f32x2 acc2[4][2];
#pragma unroll
        for (int r = 0; r < 4; ++r)
#pragma unroll
            for (int c = 0; c < 2; ++c) {
                f32x2 z = {0.0f, 0.0f};
                acc2[r][c] = z;
            }

#pragma unroll 4
        for (int k = 0; k < 64; ++k) {
            const float4 af = *(const float4*)&ldsA[k * 64 + 4 * ty];
            const float4 wf = *(const float4*)&ldsW[k * 64 + 4 * tx];
            const f32x2 w01 = {wf.x, wf.y};
            const f32x2 w23 = {wf.z, wf.w};
            const float av[4] = {af.x, af.y, af.z, af.w};
#pragma unroll
            for (int r = 0; r < 4; ++r) {
                const f32x2 avv = {av[r], av[r]};
                acc2[r][0] += avv * w01;  // -> v_pk_fma_f32
                acc2[r][1] += avv * w23;
            }
        }
        __syncthreads();  // A dead -> reuse as f32 sred

        float* sred = ldsA;
        // ---- epilogue: + P' terms, +b1, relu, * w2, partial sums ----
#pragma unroll
        for (int r = 0; r < 4; ++r) {
            const int pos = base + 4 * ty + r;
            const int s = src_csr[pos], d = dst_csr[pos];
            const float4 pb = *(const float4*)(Pb32 + (size_t)d * D + 4 * tx);
            const float4 pc = *(const float4*)(Pc32 + (size_t)s * D + 4 * tx);
            float part = 0.0f;
            float h;
            h = acc2[r][0].x + pb.x + pc.x + b1f[0];
            if (h > 0.0f) part += h * w2f[0];
            h = acc2[r][0].y + pb.y + pc.y + b1f[1];
            if (h > 0.0f) part += h * w2f[1];
            h = acc2[r][1].x + pb.z + pc.z + b1f[2];
            if (h > 0.0f) part += h * w2f[2];
            h = acc2[r][1].y + pb.w + pc.w + b1f[3];
            if (h > 0.0f) part += h * w2f[3];
            sred[(4 * ty + r) * 17 + tx] = part;
        }
        __syncthreads();

        // ---- score reduce + RelaxedBernoulli sample (one lane per slot) ----
        if (t < 64) {
            float sc_ = b2v;
#pragma unroll
            for (int i = 0; i < 16; ++i) sc_ += sred[t * 17 + i];
            const int pos = base + t;
            const int e = eord[pos];
            const float u = unoise[(size_t)LAYER * NE + e];
            const float gn = logf(u) - log1pf(-u);
            const float mar = sc_ + gn;  // decision margin; samp == (mar > 0)
            bool deferred = false;
            if (fabsf(mar) < FIXTH) {
                int slot = atomicAdd(flagcnt, 1);
                if (slot < FLAGCAP) {
                    flaglist[slot] = pos;
                    deferred = true;  // k_fix decides + writes this edge
                }
            }
            if (!deferred) {
                const float pre = 1.0f / (1.0f + expf(-sc_));
                const bool samp = mar > 0.0f;
                const float ewo = (LAYER == 0) ? ewin[e] : ew_csr[pos];
                const float ewn = samp ? alpha * ewo + (1.0f - alpha) * pre : 0.0f;
                ew_csr[pos] = ewn;
                if (LAYER == NL - 1) {
                    out[OUT_EW + (size_t)e] = ewn;
                    out[OUT_PA + (size_t)e] = pre;
                }
            }
        }
        __syncthreads();
    }
}

// ---- exact f64 re-decision for near-threshold edges (one wave per edge) ----
template <int LAYER>
__global__ __launch_bounds__(256) void k_fix(const float* __restrict__ xsrc,
                                             const int* __restrict__ src_csr,
                                             const int* __restrict__ dst_csr,
                                             const int* __restrict__ eord,
                                             const float* __restrict__ ewin,
                                             float* __restrict__ ew_csr,
                                             const float* __restrict__ unoise,
                                             const float* __restrict__ epW1,
                                             const float* __restrict__ epb1,
                                             const float* __restrict__ epW2,
                                             const float* __restrict__ epb2,
                                             const float* __restrict__ alphap,
                                             const float* __restrict__ Pb32,
                                             const float* __restrict__ Pc32,
                                             const int* __restrict__ flagcnt,
                                             const int* __restrict__ flaglist,
                                             float* __restrict__ out) {
    const int n = min(flagcnt[0], FLAGCAP);
    __shared__ float dxs[4][D];
    const int w = threadIdx.x >> 6, lane = threadIdx.x & 63;
    const int nw = gridDim.x * 4;
    for (int i = blockIdx.x * 4 + w; i < n; i += nw) {
        const int pos = flaglist[i];
        const int s = src_csr[pos], d = dst_csr[pos];
        // |dx| from the same f32 inputs the main kernel staged
        dxs[w][lane] = fabsf(xsrc[(size_t)d * D + lane] - xsrc[(size_t)s * D + lane]);
        // wave-internal broadcast (same-wave DS in-order)
        double h = 0.0;
#pragma unroll
        for (int k = 0; k < D; ++k) h += (double)dxs[w][k] * (double)epW1[k * D + lane];
        h += (double)Pb32[(size_t)d * D + lane] + (double)Pc32[(size_t)s * D + lane] +
             (double)epb1[lane];
        double part = (h > 0.0) ? h * (double)epW2[lane] : 0.0;
#pragma unroll
        for (int off = 32; off; off >>= 1) part += __shfl_xor(part, off);
        if (lane == 0) {
            const double sc_ = part + (double)epb2[0];
            const int e = eord[pos];
            const double u = (double)unoise[(size_t)LAYER * NE + e];
            const double gn = log(u) - log1p(-u);
            const double pre = 1.0 / (1.0 + exp(-sc_));
            const bool samp = (sc_ + gn) > 0.0;
            const double ewo = (LAYER == 0) ? (double)ewin[e] : (double)ew_csr[pos];
            const double alpha = (double)alphap[0];
            const double ewn = samp ? alpha * ewo + (1.0 - alpha) * pre : 0.0;
            ew_csr[pos] = (float)ewn;
            if (LAYER == NL - 1) {
                out[OUT_EW + (size_t)e] = (float)ewn;
                out[OUT_PA + (size_t)e] = (float)pre;
            }
        }
    }
}

// ---- node update: CSR gather (row-parallel loads) + GIN mlp + BN partials --
// Lane = (slot e=0..3, quarter q=0..15). Packed f32x2 gather FMAs (per-
// component order = R23 scalar, bit-same). Matvec: wgT[64][65] transposed
// weights (stride-65 -> 2-way free), 16x ds_read_b128 each side, packed
// f32x2 with 2 partial accumulators. BN stats f64 from f32 h.
template <int LAYER>
__global__ __launch_bounds__(256) void k_nodeup(const float* __restrict__ xsrc,
                                                const float* __restrict__ ew_csr,
                                                const int* __restrict__ src_csr,
                                                const int* __restrict__ rowptr,
                                                const float* __restrict__ ginW,
                                                const float* __restrict__ ginB,
                                                float* __restrict__ xh,
                                                double* __restrict__ bnacc) {
    __shared__ __align__(16) float wgT[D][65];  // wgT[c][i] = W[i][c]
    __shared__ __align__(16) float rowbuf[4][D];
    __shared__ double bn1[4][D];
    __shared__ double bn2[4][D];
    const int t = threadIdx.x, w = t >> 6, lane = t & 63;
    const int e = lane >> 4, q = lane & 15;  // slot, quarter (dims 4q..4q+3)
    for (int idx = t; idx < D * D; idx += 256) {
        const int i = idx >> 6, c = idx & 63;
        wgT[c][i] = ginW[LAYER * D * D + idx];  // idx = i*D + c
    }
    const float bj = ginB[LAYER * D + lane];
    __syncthreads();
    double s1 = 0.0, s2 = 0.0;
    const int nwaves = gridDim.x * 4;
    for (int n = blockIdx.x * 4 + w; n < NN; n += nwaves) {
        const int rs = rowptr[n], re = rowptr[n + 1];
        const int deg = re - rs;
        // ---- first 16 edges: 4 masked slots x 4 chunks, all loads up front
        const int i0 = rs + ((e < deg) ? e : 0);
        const int i1 = rs + ((4 + e < deg) ? 4 + e : 0);
        const int i2 = rs + ((8 + e < deg) ? 8 + e : 0);
        const int i3 = rs + ((12 + e < deg) ? 12 + e : 0);
        const float w0 = (e < deg) ? ew_csr[i0] : 0.f;
        const float w1 = (4 + e < deg) ? ew_csr[i1] : 0.f;
        const float w2 = (8 + e < deg) ? ew_csr[i2] : 0.f;
        const float w3 = (12 + e < deg) ? ew_csr[i3] : 0.f;
        const int s0 = src_csr[i0], s1_ = src_csr[i1];
        const int s2_ = src_csr[i2], s3_ = src_csr[i3];
        const float4 r0 = *(const float4*)(xsrc + (size_t)s0 * D + 4 * q);
        const float4 r1 = *(const float4*)(xsrc + (size_t)s1_ * D + 4 * q);
        const float4 r2 = *(const float4*)(xsrc + (size_t)s2_ * D + 4 * q);
        const float4 r3 = *(const float4*)(xsrc + (size_t)s3_ * D + 4 * q);
        const float4 rf = *(const float4*)(xsrc + (size_t)n * D + 4 * q);  // self
        f32x2 a01, a23;
        {
            const f32x2 w0v = {w0, w0}, w1v = {w1, w1}, w2v = {w2, w2}, w3v = {w3, w3};
            const f32x2 r0a = {r0.x, r0.y}, r0b = {r0.z, r0.w};
            const f32x2 r1a = {r1.x, r1.y}, r1b = {r1.z, r1.w};
            const f32x2 r2a = {r2.x, r2.y}, r2b = {r2.z, r2.w};
            const f32x2 r3a = {r3.x, r3.y}, r3b = {r3.z, r3.w};
            a01 = w0v * r0a;
            a23 = w0v * r0b;
            a01 += w1v * r1a;
            a23 += w1v * r1b;
            a01 += w2v * r2a;
            a23 += w2v * r2b;
            a01 += w3v * r3a;
            a23 += w3v * r3b;
        }
        // ---- tail: edges beyond 16, masked chunks of 4 (wave-uniform bound)
        for (int k = rs + 16; k < re; k += 4) {
            const int kk = k + e;
            const bool v = kk < re;
            const float wt = v ? ew_csr[kk] : 0.f;
            const int st = src_csr[v ? kk : rs];
            const float4 rt = *(const float4*)(xsrc + (size_t)st * D + 4 * q);
            const f32x2 wtv = {wt, wt};
            const f32x2 rta = {rt.x, rt.y}, rtb = {rt.z, rt.w};
            a01 += wtv * rta;
            a23 += wtv * rtb;
        }
        float a0 = a01.x, a1 = a01.y, a2 = a23.x, a3 = a23.y;
        // ---- tree-reduce the 4 slots (lanes differing in bits 4,5) ----
        a0 += __shfl_xor(a0, 16);
        a1 += __shfl_xor(a1, 16);
        a2 += __shfl_xor(a2, 16);
        a3 += __shfl_xor(a3, 16);
        a0 += __shfl_xor(a0, 32);
        a1 += __shfl_xor(a1, 32);
        a2 += __shfl_xor(a2, 32);
        a3 += __shfl_xor(a3, 32);
        // ---- + self, publish to rowbuf (same-wave DS in-order) ----
        if (e == 0) {
            rowbuf[w][4 * q + 0] = a0 + rf.x;
            rowbuf[w][4 * q + 1] = a1 + rf.y;
            rowbuf[w][4 * q + 2] = a2 + rf.z;
            rowbuf[w][4 * q + 3] = a3 + rf.w;
        }
        // ---- GIN matvec (packed f32, transposed weights) ----
        f32x2 h01 = {bj, 0.0f}, h23 = {0.0f, 0.0f};
#pragma unroll
        for (int ib = 0; ib < 16; ++ib) {
            const float4 rb = *(const float4*)&rowbuf[w][4 * ib];   // broadcast
            const float4 wv = *(const float4*)&wgT[lane][4 * ib];   // own column
            const f32x2 ra = {rb.x, rb.y}, rc = {rb.z, rb.w};
            const f32x2 wa = {wv.x, wv.y}, wc = {wv.z, wv.w};
            h01 += ra * wa;
            h23 += rc * wc;
        }
        float h = (h01.x + h01.y) + (h23.x + h23.y);
        h = h > 0.0f ? h : 0.0f;
        xh[(size_t)n * D + lane] = h;
        s1 += (double)h;
        s2 += (double)h * (double)h;
    }
    // ---- block-level reduce, then 2 atomics per lane-column per block ----
    bn1[w][lane] = s1;
    bn2[w][lane] = s2;
    __syncthreads();
    if (w == 0) {
        atomAdd64(&bnacc[lane], bn1[0][lane] + bn1[1][lane] + bn1[2][lane] + bn1[3][lane]);
        atomAdd64(&bnacc[64 + lane], bn2[0][lane] + bn2[1][lane] + bn2[2][lane] + bn2[3][lane]);
    }
}

// ---- BN finalize ----
__global__ __launch_bounds__(64) void k_bnfin(int layer, const float* __restrict__ gamma,
                                              const float* __restrict__ beta,
                                              const double* __restrict__ bnacc,
                                              double* __restrict__ bnsc) {
    int j = threadIdx.x;
    double mu = bnacc[j] * (1.0 / NN);
    double var = bnacc[64 + j] * (1.0 / NN) - mu * mu;
    double sc = (double)gamma[layer * D + j] / sqrt(var + 1e-5);
    bnsc[j] = sc;
    bnsc[64 + j] = (double)beta[layer * D + j] - mu * sc;
}

// ---- att1 (+fused BN apply): v = bnsc*xh+off -> x32/out; score vs centroid -
template <int LAYER>
__global__ __launch_bounds__(256) void k_att1(const float* __restrict__ xh,
                                              const double* __restrict__ bnsc,
                                              const double* __restrict__ c64,
                                              float* __restrict__ x32,
                                              float* __restrict__ out,
                                              double* __restrict__ sc,
                                              double* __restrict__ bmax) {
    const int blk = blockIdx.x, t = threadIdx.x, w = t >> 6, lane = t & 63;
    const int g = blk >> 6;
    __shared__ double wmax[4];
    const double cj = c64[g * D + lane];
    const double bsc = bnsc[lane], boff = bnsc[64 + lane];
    double locmax = -1e300;
    for (int m = 0; m < 16; ++m) {
        const int n = blk * 64 + w * 16 + m;
        const float v32 = (float)(bsc * (double)xh[(size_t)n * D + lane] + boff);
        x32[(size_t)n * D + lane] = v32;
        if (LAYER == NL - 1) out[OUT_X + (size_t)n * D + lane] = v32;
        double v = (double)v32 * cj;
#pragma unroll
        for (int off = 32; off; off >>= 1) v += __shfl_xor(v, off);
        if (lane == 0) sc[n] = v;
        locmax = fmax(locmax, v);
    }
    if (lane == 0) wmax[w] = locmax;
    __syncthreads();
    if (t == 0) bmax[blk] = fmax(fmax(wmax[0], wmax[1]), fmax(wmax[2], wmax[3]));
}

__global__ __launch_bounds__(64) void k_att2(const double* __restrict__ bmax,
                                             double* __restrict__ mxg,
                                             double* __restrict__ num,
                                             double* __restrict__ den) {
    const int g = blockIdx.x, t = threadIdx.x;
    double m = bmax[g * 64 + t];
#pragma unroll
    for (int off = 32; off; off >>= 1) m = fmax(m, __shfl_xor(m, off));
    if (t == 0) {
        mxg[g] = m;
        den[g] = 0.0;
    }
    num[g * D + t] = 0.0;
}

__global__ __launch_bounds__(256) void k_att3(const float* __restrict__ x32,
                                              const double* __restrict__ sc,
                                              const double* __restrict__ mxg,
                                              double* __restrict__ num,
                                              double* __restrict__ den) {
    const int blk = blockIdx.x, t = threadIdx.x, w = t >> 6, lane = t & 63;
    const int g = blk >> 6;
    __shared__ double cp[4][D];
    __shared__ double wes[4];
    const double mx = mxg[g];
    double accj = 0.0, esum = 0.0;
    for (int m = 0; m < 16; ++m) {
        const int n = blk * 64 + w * 16 + m;
        const double e = exp(sc[n] - mx);
        accj += e * (double)x32[(size_t)n * D + lane];
        esum += e;
    }
    cp[w][lane] = accj;
    if (lane == 0) wes[w] = esum;
    __syncthreads();
    if (t < D) {
        atomAdd64(&num[g * D + t], cp[0][t] + cp[1][t] + cp[2][t] + cp[3][t]);
        if (t == 0) atomAdd64(&den[g], wes[0] + wes[1] + wes[2] + wes[3]);
    }
}

__global__ __launch_bounds__(64) void k_att4(const double* __restrict__ num,
                                             const double* __restrict__ den,
                                             double* __restrict__ c64) {
    const int g = blockIdx.x, t = threadIdx.x;
    c64[g * D + t] = num[g * D + t] / den[g];
}

// ---- head: relu(x@W1+b1)@W2+b2 for all nodes + 16 centroid rows (f32) ----
__global__ __launch_bounds__(256) void k_head(const float* __restrict__ x32,
                                              const double* __restrict__ c64,
                                              const float* __restrict__ hW1,
                                              const float* __restrict__ hb1,
                                              const float* __restrict__ hW2,
                                              const float* __restrict__ hb2,
                                              float* __restrict__ out) {
    __shared__ float w1[D * D];
    __shared__ float w2[D * D];
    __shared__ float xr[4][D];
    __shared__ float hr[4][D];
    int tid = threadIdx.x, w = tid >> 6, j = tid & 63;
    for (int idx = tid; idx < D * D; idx += 256) {
        w1[idx] = hW1[idx];
        w2[idx] = hW2[idx];
    }
    const float b1j = hb1[j];
    const float b2j = hb2[j];
    __syncthreads();
    const int ROWS = NN + BSZ;
    for (int grp = blockIdx.x; grp * 4 < ROWS; grp += gridDim.x) {
        int r = grp * 4 + w;
        bool valid = r < ROWS;
        float xv = 0.f;
        if (valid)
            xv = (r < NN) ? x32[(size_t)r * D + j] : (float)c64[(size_t)(r - NN) * D + j];
        xr[w][j] = xv;
        __syncthreads();
        if (valid) {
            float h = b1j;
#pragma unroll
            for (int i = 0; i < D; ++i) h += xr[w][i] * w1[i * D + j];
            hr[w][j] = h > 0.f ? h : 0.f;
        }
        __syncthreads();
        if (valid) {
            float o = b2j;
#pragma unroll
            for (int i = 0; i < D; ++i) o += hr[w][i] * w2[i * D + j];
            if (r < NN) {
                out[OUT_XL + (size_t)r * D + j] = o;
            } else {
                size_t cr = (size_t)(r - NN) * D + j;
                out[OUT_CL + cr] = o;
                out[OUT_C + cr] = (float)c64[cr];
            }
        }
        __syncthreads();
    }
}

extern "C" void kernel_launch(void* const* d_in, const int* in_sizes, int n_in,
                              void* d_out, int out_size, void* d_ws, size_t ws_size,
                              hipStream_t stream) {
    const float* xin    = (const float*)d_in[0];
    const int*   ei     = (const int*)d_in[1];
    const float* ewin   = (const float*)d_in[2];
    const float* unoise = (const float*)d_in[5];
    const float* epW1   = (const float*)d_in[6];
    const float* epb1   = (const float*)d_in[7];
    const float* epW2   = (const float*)d_in[8];
    const float* epb2   = (const float*)d_in[9];
    const float* alphap = (const float*)d_in[10];
    const float* ginW   = (const float*)d_in[11];
    const float* ginB   = (const float*)d_in[12];
    const float* bng    = (const float*)d_in[13];
    const float* bnb    = (const float*)d_in[14];
    const float* hW1    = (const float*)d_in[15];
    const float* hb1    = (const float*)d_in[16];
    const float* hW2    = (const float*)d_in[17];
    const float* hb2    = (const float*)d_in[18];
    float* out = (float*)d_out;
    const int* esrc = ei;
    const int* edst = ei + NE;

    char* ws = (char*)d_ws;
    const size_t SZ4 = (size_t)NN * D * sizeof(float);  // 16MB
    // Pb (k_P->k_edge/k_fix) and xh (k_nodeup->k_att1): disjoint live ranges.
    float* Pb32 = (float*)(ws);
    float* xh32 = Pb32;  // alias
    float* Pc32 = (float*)(ws + SZ4);
    float* x32  = (float*)(ws + 2 * SZ4);
    float* ew_csr = (float*)(ws + 3 * SZ4);                       // NE*4 = 4MB
    double* sc  = (double*)(ws + 3 * SZ4 + (size_t)NE * 4);       // NN*8
    char*  p    = ws + 3 * SZ4 + (size_t)NE * 4 + (size_t)NN * 8;
    double* c64  = (double*)p;          p += BSZ * D * 8;
    double* qb   = (double*)p;          p += BSZ * D * 8;
    double* qc   = (double*)p;          p += BSZ * D * 8;
    double* bnacc = (double*)p;         p += 128 * 8;
    double* bnsc  = (double*)p;         p += 128 * 8;
    double* bmax  = (double*)p;         p += 1024 * 8;
    double* mxg   = (double*)p;         p += 16 * 8;
    double* num   = (double*)p;         p += BSZ * D * 8;
    double* den   = (double*)p;         p += 16 * 8;
    // CSR
    int* cnt     = (int*)p;             p += (size_t)NN * 4;
    int* rowptr  = (int*)p;             p += (size_t)(NN + 1) * 4 + 4;
    int* cursor  = (int*)p;             p += (size_t)NN * 4;
    int* bsum    = (int*)p;             p += 256 * 4;
    int* eord    = (int*)p;             p += (size_t)NE * 4;
    int* src_csr = (int*)p;             p += (size_t)NE * 4;
    int* dst_csr = (int*)p;             p += (size_t)NE * 4;
    // near-threshold fixup list
    int* flagcnt  = (int*)p;            p += 8;
    int* flaglist = (int*)p;            p += (size_t)FLAGCAP * 4;

    // ---- CSR build (dst static) ----
    hipMemsetAsync(cnt, 0, (size_t)NN * 4, stream);
    k_deg<<<1024, 256, 0, stream>>>(edst, cnt);
    k_scan1<<<256, 256, 0, stream>>>(cnt, rowptr, bsum);
    k_scan2<<<1, 256, 0, stream>>>(bsum);
    k_scan3<<<256, 256, 0, stream>>>(bsum, rowptr, cursor);
    k_fill<<<1024, 256, 0, stream>>>(esrc, edst, cursor, eord, src_csr, dst_csr);

    hipMemsetAsync(c64, 0, (size_t)BSZ * D * 8, stream);
    k_centroid0<<<BSZ * 8, 256, 0, stream>>>(xin, c64);

    // ---------------- layer 0 ----------------
    k_qbc<<<4, 256, 0, stream>>>(c64, epW1, qb, qc);
    k_P<0><<<2048, 256, 0, stream>>>(xin, x32, epW1, qb, qc, Pb32, Pc32, bnacc);
    hipMemsetAsync(flagcnt, 0, 4, stream);
    k_edge<0><<<2048, 256, 0, stream>>>(xin, src_csr, dst_csr, eord, ewin, ew_csr, unoise,
                                        epW1, epb1, epW2, epb2, alphap, Pb32, Pc32,
                                        flagcnt, flaglist, out);
    k_fix<0><<<64, 256, 0, stream>>>(xin, src_csr, dst_csr, eord, ewin, ew_csr, unoise,
                                     epW1, epb1, epW2, epb2, alphap, Pb32, Pc32,
                                     flagcnt, flaglist, out);
    k_nodeup<0><<<2048, 256, 0, stream>>>(xin, ew_csr, src_csr, rowptr, ginW, ginB,
                                          xh32, bnacc);
    k_bnfin<<<1, 64, 0, stream>>>(0, bng, bnb, bnacc, bnsc);
    k_att1<0><<<1024, 256, 0, stream>>>(xh32, bnsc, c64, x32, out, sc, bmax);
    k_att2<<<16, 64, 0, stream>>>(bmax, mxg, num, den);
    k_att3<<<1024, 256, 0, stream>>>(x32, sc, mxg, num, den);
    k_att4<<<16, 64, 0, stream>>>(num, den, c64);

    // ---------------- layer 1 ----------------
    k_qbc<<<4, 256, 0, stream>>>(c64, epW1, qb, qc);
    k_P<1><<<2048, 256, 0, stream>>>(xin, x32, epW1, qb, qc, Pb32, Pc32, bnacc);
    hipMemsetAsync(flagcnt, 0, 4, stream);
    k_edge<1><<<2048, 256, 0, stream>>>(x32, src_csr, dst_csr, eord, ewin, ew_csr, unoise,
                                        epW1, epb1, epW2, epb2, alphap, Pb32, Pc32,
                                        flagcnt, flaglist, out);
    k_fix<1><<<64, 256, 0, stream>>>(x32, src_csr, dst_csr, eord, ewin, ew_csr, unoise,
                                     epW1, epb1, epW2, epb2, alphap, Pb32, Pc32,
                                     flagcnt, flaglist, out);
    k_nodeup<1><<<2048, 256, 0, stream>>>(x32, ew_csr, src_csr, rowptr, ginW, ginB,
                                          xh32, bnacc);
    k_bnfin<<<1, 64, 0, stream>>>(1, bng, bnb, bnacc, bnsc);
    k_att1<1><<<1024, 256, 0, stream>>>(xh32, bnsc, c64, x32, out, sc, bmax);
    k_att2<<<16, 64, 0, stream>>>(bmax, mxg, num, den);
    k_att3<<<1024, 256, 0, stream>>>(x32, sc, mxg, num, den);
    k_att4<<<16, 64, 0, stream>>>(num, den, c64);

    // ---------------- heads + centroid output ----------------
    k_head<<<2048, 256, 0, stream>>>(x32, c64, hW1, hb1, hW2, hb2, out);
}

// Round 18
// 786.662 us; speedup vs baseline: 1.2400x; 1.0758x over previous
//
#include <hip/hip_runtime.h>
#include <hip/hip_bf16.h>

// GraphCAD forward on MI355X. All float I/O is f32.
// R24->R25: apply the proven issue-shaving recipe (transposed LDS weights
// stride-65 + b128 column reads, float4 row broadcasts, packed f32x2 FMA,
// barrier-free wave-per-row) to the remaining old-style kernels:
// (1) k_P -> wave-per-node, wbT/wcT[64][65], no barriers; (2) k_head ->
// wave-per-row, w1T/w2T; (3) attention score math f64->f32 (sc/bmax/mxg
// f32, expf, f32 shuffles; per-block partials merged via f64 atomics; BN
// affine stays f64). All continuous-path f32 relaxations in the class
// already accepted in R20/R23 (scores shift ~1e-6, FIXTH=2e-3/k_fix-f64
// guard unchanged). k_edge (latency floor, 177us), k_fix, k_nodeup, CSR,
// qbc, bnfin byte-identical to R24 (846us).

#define D 64
#define BSZ 16
#define NPG 4096
#define NN (BSZ * NPG)   // 65536 nodes
#define NE (NN * 16)     // 1048576 edges
#define NL 2
#define NTILE (NE / 64)  // 16384

#define FIXTH 2e-3f
#define FLAGCAP 65536

// output layout (elements, f32)
#define OUT_X  0u
#define OUT_EW 4194304u
#define OUT_C  5242880u
#define OUT_XL 5243904u
#define OUT_CL 9438208u
#define OUT_PA 9439232u

typedef __attribute__((ext_vector_type(2))) float f32x2;

__device__ __forceinline__ void atomAdd64(double* p, double v) { unsafeAtomicAdd(p, v); }

// ================= CSR build (dst is a static input; rebuilt per call) ======
__global__ __launch_bounds__(256) void k_deg(const int* __restrict__ edst,
                                             int* __restrict__ cnt) {
    int stride = gridDim.x * 256;
    for (int e = blockIdx.x * 256 + threadIdx.x; e < NE; e += stride)
        atomicAdd(&cnt[edst[e]], 1);
}

__global__ __launch_bounds__(256) void k_scan1(const int* __restrict__ cnt,
                                               int* __restrict__ rowptr,
                                               int* __restrict__ bsum) {
    __shared__ int sd[256];
    const int b = blockIdx.x, t = threadIdx.x;
    const int v = cnt[b * 256 + t];
    sd[t] = v;
    __syncthreads();
    for (int off = 1; off < 256; off <<= 1) {
        int tmp = (t >= off) ? sd[t - off] : 0;
        __syncthreads();
        sd[t] += tmp;
        __syncthreads();
    }
    rowptr[b * 256 + t] = sd[t] - v;  // exclusive
    if (t == 255) bsum[b] = sd[255];
}

__global__ __launch_bounds__(256) void k_scan2(int* __restrict__ bsum) {
    __shared__ int sd[256];
    const int t = threadIdx.x;
    const int v = bsum[t];
    sd[t] = v;
    __syncthreads();
    for (int off = 1; off < 256; off <<= 1) {
        int tmp = (t >= off) ? sd[t - off] : 0;
        __syncthreads();
        sd[t] += tmp;
        __syncthreads();
    }
    bsum[t] = sd[t] - v;  // exclusive
}

__global__ __launch_bounds__(256) void k_scan3(const int* __restrict__ bsum,
                                               int* __restrict__ rowptr,
                                               int* __restrict__ cursor) {
    const int i = blockIdx.x * 256 + threadIdx.x;
    const int r = rowptr[i] + bsum[blockIdx.x];
    rowptr[i] = r;
    cursor[i] = r;
    if (i == 0) rowptr[NN] = NE;
}

// fill CSR: slot -> original edge (eord), src (src_csr), dst (dst_csr).
__global__ __launch_bounds__(256) void k_fill(const int* __restrict__ esrc,
                                              const int* __restrict__ edst,
                                              int* __restrict__ cursor,
                                              int* __restrict__ eord,
                                              int* __restrict__ src_csr,
                                              int* __restrict__ dst_csr) {
    int stride = gridDim.x * 256;
    for (int e = blockIdx.x * 256 + threadIdx.x; e < NE; e += stride) {
        const int d = edst[e];
        int pos = atomicAdd(&cursor[d], 1);
        eord[pos] = e;
        src_csr[pos] = esrc[e];
        dst_csr[pos] = d;
    }
}

// ---- initial centroid: per-graph mean of x (f32 in, f64 out), 8 blocks/graph
__global__ __launch_bounds__(256) void k_centroid0(const float* __restrict__ xin,
                                                   double* __restrict__ c64) {
    const int g = blockIdx.x >> 3, sub = blockIdx.x & 7, tid = threadIdx.x;
    const int r = tid >> 6, f = tid & 63;
    __shared__ double cr[4][D];
    double s = 0.0;
    for (int k = 0; k < NPG / 8 / 4; ++k) {
        size_t n = (size_t)g * NPG + (size_t)(sub * (NPG / 8) + 4 * k + r);
        s += (double)xin[n * D + f];
    }
    cr[r][f] = s;
    __syncthreads();
    if (tid < D)
        atomAdd64(&c64[g * D + tid],
                  (cr[0][tid] + cr[1][tid] + cr[2][tid] + cr[3][tid]) * (1.0 / NPG));
}

// ---- qb = c @ W1b, qc = c @ W1c (per graph, f64) ----
__global__ __launch_bounds__(256) void k_qbc(const double* __restrict__ c64,
                                             const float* __restrict__ epW1,
                                             double* __restrict__ qb, double* __restrict__ qc) {
    int gj = blockIdx.x * 256 + threadIdx.x;
    if (gj >= BSZ * D) return;
    int g = gj >> 6, j = gj & 63;
    double sb = 0.0, sc = 0.0;
#pragma unroll
    for (int i = 0; i < D; ++i) {
        double cv = c64[g * D + i];
        sb += cv * (double)epW1[(D + i) * D + j];
        sc += cv * (double)epW1[(2 * D + i) * D + j];
    }
    qb[gj] = sb;
    qc[gj] = sc;
}

// ---- P'_b = x@W1b - qb[g], P'_c = x@W1c - qc[g]; f32, wave-per-node ----
// Transposed weights wbT/wcT[64][65] (stride-65, 2-way free), b128 reads,
// packed f32x2 FMAs, zero in-loop barriers (same-wave DS in-order).
template <int LAYER>
__global__ __launch_bounds__(256) void k_P(const float* __restrict__ xin,
                                           const float* __restrict__ x32,
                                           const float* __restrict__ epW1,
                                           const double* __restrict__ qb,
                                           const double* __restrict__ qc,
                                           float* __restrict__ Pb, float* __restrict__ Pc,
                                           double* __restrict__ bnacc) {
    if (blockIdx.x == 0 && threadIdx.x < 128) bnacc[threadIdx.x] = 0.0;
    __shared__ __align__(16) float wbT[D][65];  // wbT[c][i] = W1b[i][c]
    __shared__ __align__(16) float wcT[D][65];
    __shared__ __align__(16) float rowbuf[4][D];
    const int t = threadIdx.x, w = t >> 6, lane = t & 63;
    for (int idx = t; idx < D * D; idx += 256) {
        const int i = idx >> 6, c = idx & 63;
        wbT[c][i] = epW1[(D + i) * D + c];
        wcT[c][i] = epW1[(2 * D + i) * D + c];
    }
    __syncthreads();
    const int nwaves = gridDim.x * 4;
    for (int n = blockIdx.x * 4 + w; n < NN; n += nwaves) {
        const float xv = (LAYER == 0) ? xin[(size_t)n * D + lane] : x32[(size_t)n * D + lane];
        rowbuf[w][lane] = xv;  // same-wave DS in-order
        f32x2 pb2 = {0.0f, 0.0f}, pc2 = {0.0f, 0.0f};
#pragma unroll
        for (int ib = 0; ib < 16; ++ib) {
            const float4 rb = *(const float4*)&rowbuf[w][4 * ib];   // broadcast
            const float4 wbv = *(const float4*)&wbT[lane][4 * ib];  // own column
            const float4 wcv = *(const float4*)&wcT[lane][4 * ib];
            const f32x2 ra = {rb.x, rb.y}, rc = {rb.z, rb.w};
            const f32x2 wb01 = {wbv.x, wbv.y}, wb23 = {wbv.z, wbv.w};
            const f32x2 wc01 = {wcv.x, wcv.y}, wc23 = {wcv.z, wcv.w};
            pb2 += ra * wb01;
            pb2 += rc * wb23;
            pc2 += ra * wc01;
            pc2 += rc * wc23;
        }
        const int g = n >> 12;
        Pb[(size_t)n * D + lane] = (pb2.x + pb2.y) - (float)qb[g * D + lane];
        Pc[(size_t)n * D + lane] = (pc2.x + pc2.y) - (float)qc[g * D + lane];
    }
}

// ---- edge scorer, CSR order: all-f32 tile GEMM (packed f32x2 acc) ----
// Near-threshold edges (|score+g| < FIXTH) deferred to k_fix (f64).
// LDS: A f32 [64][64] (reused as sred, stride 17), W f32 [64][64] = 32768B.
template <int LAYER>
__global__ __launch_bounds__(256, 4) void k_edge(const float* __restrict__ xsrc,
                                                 const int* __restrict__ src_csr,
                                                 const int* __restrict__ dst_csr,
                                                 const int* __restrict__ eord,
                                                 const float* __restrict__ ewin,
                                                 float* __restrict__ ew_csr,
                                                 const float* __restrict__ unoise,
                                                 const float* __restrict__ epW1,
                                                 const float* __restrict__ epb1,
                                                 const float* __restrict__ epW2,
                                                 const float* __restrict__ epb2,
                                                 const float* __restrict__ alphap,
                                                 const float* __restrict__ Pb32,
                                                 const float* __restrict__ Pc32,
                                                 int* __restrict__ flagcnt,
                                                 int* __restrict__ flaglist,
                                                 float* __restrict__ out) {
    const int t = threadIdx.x;
    const int tx = t & 15, ty = t >> 4;

    __shared__ __align__(16) float ldsA[64 * 64];  // |dx| [dim][slot]
    __shared__ __align__(16) float ldsW[64 * 64];  // W1a [k][j]

    for (int idx = t; idx < D * D; idx += 256) {
        ldsW[idx] = epW1[idx];  // [k][j] layout matches epW1 row-major
    }
    float b1f[4], w2f[4];
#pragma unroll
    for (int c = 0; c < 4; ++c) {
        b1f[c] = epb1[4 * tx + c];
        w2f[c] = epW2[4 * tx + c];
    }
    const float b2v = epb2[0];
    const float alpha = alphap[0];
    __syncthreads();

    const int eloc = t >> 2, q = t & 3;

    for (int tile = blockIdx.x; tile < NTILE; tile += gridDim.x) {
        const int base = tile * 64;

        // ---- stage |x_d - x_s| (f32, transposed). d-rows run-repeat (L1). --
        {
            const int pos = base + eloc;
            const int s = src_csr[pos], d = dst_csr[pos];
            const float* rs = xsrc + (size_t)s * D + q * 16;
            const float* rd = xsrc + (size_t)d * D + q * 16;
#pragma unroll
            for (int c = 0; c < 4; ++c) {
                const float4 fd = *(const float4*)(rd + 4 * c);
                const float4 fs = *(const float4*)(rs + 4 * c);
                const int dim = q * 16 + 4 * c;
                ldsA[(dim + 0) * 64 + eloc] = fabsf(fd.x - fs.x);
                ldsA[(dim + 1) * 64 + eloc] = fabsf(fd.y - fs.y);
                ldsA[(dim + 2) * 64 + eloc] = fabsf(fd.z - fs.z);
                ldsA[(dim + 3) * 64 + eloc] = fabsf(fd.w - fs.w);
            }
        }
        __syncthreads();

        // ---- 64x64x64 GEMM: f32 inputs, packed f32x2 accumulate ----
        f32x2 acc2[4][2];
#pragma unroll
        for (int r = 0; r < 4; ++r)
#pragma unroll
            for (int c = 0; c < 2; ++c) {
                f32x2 z = {0.0f, 0.0f};
                acc2[r][c] = z;
            }

#pragma unroll 4
        for (int k = 0; k < 64; ++k) {
            const float4 af = *(const float4*)&ldsA[k * 64 + 4 * ty];
            const float4 wf = *(const float4*)&ldsW[k * 64 + 4 * tx];
            const f32x2 w01 = {wf.x, wf.y};
            const f32x2 w23 = {wf.z, wf.w};
            const float av[4] = {af.x, af.y, af.z, af.w};
#pragma unroll
            for (int r = 0; r < 4; ++r) {
                const f32x2 avv = {av[r], av[r]};
                acc2[r][0] += avv * w01;  // -> v_pk_fma_f32
                acc2[r][1] += avv * w23;
            }
        }
        __syncthreads();  // A dead -> reuse as f32 sred

        float* sred = ldsA;
        // ---- epilogue: + P' terms, +b1, relu, * w2, partial sums ----
#pragma unroll
        for (int r = 0; r < 4; ++r) {
            const int pos = base + 4 * ty + r;
            const int s = src_csr[pos], d = dst_csr[pos];
            const float4 pb = *(const float4*)(Pb32 + (size_t)d * D + 4 * tx);
            const float4 pc = *(const float4*)(Pc32 + (size_t)s * D + 4 * tx);
            float part = 0.0f;
            float h;
            h = acc2[r][0].x + pb.x + pc.x + b1f[0];
            if (h > 0.0f) part += h * w2f[0];
            h = acc2[r][0].y + pb.y + pc.y + b1f[1];
            if (h > 0.0f) part += h * w2f[1];
            h = acc2[r][1].x + pb.z + pc.z + b1f[2];
            if (h > 0.0f) part += h * w2f[2];
            h = acc2[r][1].y + pb.w + pc.w + b1f[3];
            if (h > 0.0f) part += h * w2f[3];
            sred[(4 * ty + r) * 17 + tx] = part;
        }
        __syncthreads();

        // ---- score reduce + RelaxedBernoulli sample (one lane per slot) ----
        if (t < 64) {
            float sc_ = b2v;
#pragma unroll
            for (int i = 0; i < 16; ++i) sc_ += sred[t * 17 + i];
            const int pos = base + t;
            const int e = eord[pos];
            const float u = unoise[(size_t)LAYER * NE + e];
            const float gn = logf(u) - log1pf(-u);
            const float mar = sc_ + gn;  // decision margin; samp == (mar > 0)
            bool deferred = false;
            if (fabsf(mar) < FIXTH) {
                int slot = atomicAdd(flagcnt, 1);
                if (slot < FLAGCAP) {
                    flaglist[slot] = pos;
                    deferred = true;  // k_fix decides + writes this edge
                }
            }
            if (!deferred) {
                const float pre = 1.0f / (1.0f + expf(-sc_));
                const bool samp = mar > 0.0f;
                const float ewo = (LAYER == 0) ? ewin[e] : ew_csr[pos];
                const float ewn = samp ? alpha * ewo + (1.0f - alpha) * pre : 0.0f;
                ew_csr[pos] = ewn;
                if (LAYER == NL - 1) {
                    out[OUT_EW + (size_t)e] = ewn;
                    out[OUT_PA + (size_t)e] = pre;
                }
            }
        }
        __syncthreads();
    }
}

// ---- exact f64 re-decision for near-threshold edges (one wave per edge) ----
template <int LAYER>
__global__ __launch_bounds__(256) void k_fix(const float* __restrict__ xsrc,
                                             const int* __restrict__ src_csr,
                                             const int* __restrict__ dst_csr,
                                             const int* __restrict__ eord,
                                             const float* __restrict__ ewin,
                                             float* __restrict__ ew_csr,
                                             const float* __restrict__ unoise,
                                             const float* __restrict__ epW1,
                                             const float* __restrict__ epb1,
                                             const float* __restrict__ epW2,
                                             const float* __restrict__ epb2,
                                             const float* __restrict__ alphap,
                                             const float* __restrict__ Pb32,
                                             const float* __restrict__ Pc32,
                                             const int* __restrict__ flagcnt,
                                             const int* __restrict__ flaglist,
                                             float* __restrict__ out) {
    const int n = min(flagcnt[0], FLAGCAP);
    __shared__ float dxs[4][D];
    const int w = threadIdx.x >> 6, lane = threadIdx.x & 63;
    const int nw = gridDim.x * 4;
    for (int i = blockIdx.x * 4 + w; i < n; i += nw) {
        const int pos = flaglist[i];
        const int s = src_csr[pos], d = dst_csr[pos];
        // |dx| from the same f32 inputs the main kernel staged
        dxs[w][lane] = fabsf(xsrc[(size_t)d * D + lane] - xsrc[(size_t)s * D + lane]);
        // wave-internal broadcast (same-wave DS in-order)
        double h = 0.0;
#pragma unroll
        for (int k = 0; k < D; ++k) h += (double)dxs[w][k] * (double)epW1[k * D + lane];
        h += (double)Pb32[(size_t)d * D + lane] + (double)Pc32[(size_t)s * D + lane] +
             (double)epb1[lane];
        double part = (h > 0.0) ? h * (double)epW2[lane] : 0.0;
#pragma unroll
        for (int off = 32; off; off >>= 1) part += __shfl_xor(part, off);
        if (lane == 0) {
            const double sc_ = part + (double)epb2[0];
            const int e = eord[pos];
            const double u = (double)unoise[(size_t)LAYER * NE + e];
            const double gn = log(u) - log1p(-u);
            const double pre = 1.0 / (1.0 + exp(-sc_));
            const bool samp = (sc_ + gn) > 0.0;
            const double ewo = (LAYER == 0) ? (double)ewin[e] : (double)ew_csr[pos];
            const double alpha = (double)alphap[0];
            const double ewn = samp ? alpha * ewo + (1.0 - alpha) * pre : 0.0;
            ew_csr[pos] = (float)ewn;
            if (LAYER == NL - 1) {
                out[OUT_EW + (size_t)e] = (float)ewn;
                out[OUT_PA + (size_t)e] = (float)pre;
            }
        }
    }
}

// ---- node update: CSR gather (row-parallel loads) + GIN mlp + BN partials --
template <int LAYER>
__global__ __launch_bounds__(256) void k_nodeup(const float* __restrict__ xsrc,
                                                const float* __restrict__ ew_csr,
                                                const int* __restrict__ src_csr,
                                                const int* __restrict__ rowptr,
                                                const float* __restrict__ ginW,
                                                const float* __restrict__ ginB,
                                                float* __restrict__ xh,
                                                double* __restrict__ bnacc) {
    __shared__ __align__(16) float wgT[D][65];  // wgT[c][i] = W[i][c]
    __shared__ __align__(16) float rowbuf[4][D];
    __shared__ double bn1[4][D];
    __shared__ double bn2[4][D];
    const int t = threadIdx.x, w = t >> 6, lane = t & 63;
    const int e = lane >> 4, q = lane & 15;  // slot, quarter (dims 4q..4q+3)
    for (int idx = t; idx < D * D; idx += 256) {
        const int i = idx >> 6, c = idx & 63;
        wgT[c][i] = ginW[LAYER * D * D + idx];  // idx = i*D + c
    }
    const float bj = ginB[LAYER * D + lane];
    __syncthreads();
    double s1 = 0.0, s2 = 0.0;
    const int nwaves = gridDim.x * 4;
    for (int n = blockIdx.x * 4 + w; n < NN; n += nwaves) {
        const int rs = rowptr[n], re = rowptr[n + 1];
        const int deg = re - rs;
        // ---- first 16 edges: 4 masked slots x 4 chunks, all loads up front
        const int i0 = rs + ((e < deg) ? e : 0);
        const int i1 = rs + ((4 + e < deg) ? 4 + e : 0);
        const int i2 = rs + ((8 + e < deg) ? 8 + e : 0);
        const int i3 = rs + ((12 + e < deg) ? 12 + e : 0);
        const float w0 = (e < deg) ? ew_csr[i0] : 0.f;
        const float w1 = (4 + e < deg) ? ew_csr[i1] : 0.f;
        const float w2 = (8 + e < deg) ? ew_csr[i2] : 0.f;
        const float w3 = (12 + e < deg) ? ew_csr[i3] : 0.f;
        const int s0 = src_csr[i0], s1_ = src_csr[i1];
        const int s2_ = src_csr[i2], s3_ = src_csr[i3];
        const float4 r0 = *(const float4*)(xsrc + (size_t)s0 * D + 4 * q);
        const float4 r1 = *(const float4*)(xsrc + (size_t)s1_ * D + 4 * q);
        const float4 r2 = *(const float4*)(xsrc + (size_t)s2_ * D + 4 * q);
        const float4 r3 = *(const float4*)(xsrc + (size_t)s3_ * D + 4 * q);
        const float4 rf = *(const float4*)(xsrc + (size_t)n * D + 4 * q);  // self
        f32x2 a01, a23;
        {
            const f32x2 w0v = {w0, w0}, w1v = {w1, w1}, w2v = {w2, w2}, w3v = {w3, w3};
            const f32x2 r0a = {r0.x, r0.y}, r0b = {r0.z, r0.w};
            const f32x2 r1a = {r1.x, r1.y}, r1b = {r1.z, r1.w};
            const f32x2 r2a = {r2.x, r2.y}, r2b = {r2.z, r2.w};
            const f32x2 r3a = {r3.x, r3.y}, r3b = {r3.z, r3.w};
            a01 = w0v * r0a;
            a23 = w0v * r0b;
            a01 += w1v * r1a;
            a23 += w1v * r1b;
            a01 += w2v * r2a;
            a23 += w2v * r2b;
            a01 += w3v * r3a;
            a23 += w3v * r3b;
        }
        // ---- tail: edges beyond 16, masked chunks of 4 (wave-uniform bound)
        for (int k = rs + 16; k < re; k += 4) {
            const int kk = k + e;
            const bool v = kk < re;
            const float wt = v ? ew_csr[kk] : 0.f;
            const int st = src_csr[v ? kk : rs];
            const float4 rt = *(const float4*)(xsrc + (size_t)st * D + 4 * q);
            const f32x2 wtv = {wt, wt};
            const f32x2 rta = {rt.x, rt.y}, rtb = {rt.z, rt.w};
            a01 += wtv * rta;
            a23 += wtv * rtb;
        }
        float a0 = a01.x, a1 = a01.y, a2 = a23.x, a3 = a23.y;
        // ---- tree-reduce the 4 slots (lanes differing in bits 4,5) ----
        a0 += __shfl_xor(a0, 16);
        a1 += __shfl_xor(a1, 16);
        a2 += __shfl_xor(a2, 16);
        a3 += __shfl_xor(a3, 16);
        a0 += __shfl_xor(a0, 32);
        a1 += __shfl_xor(a1, 32);
        a2 += __shfl_xor(a2, 32);
        a3 += __shfl_xor(a3, 32);
        // ---- + self, publish to rowbuf (same-wave DS in-order) ----
        if (e == 0) {
            rowbuf[w][4 * q + 0] = a0 + rf.x;
            rowbuf[w][4 * q + 1] = a1 + rf.y;
            rowbuf[w][4 * q + 2] = a2 + rf.z;
            rowbuf[w][4 * q + 3] = a3 + rf.w;
        }
        // ---- GIN matvec (packed f32, transposed weights) ----
        f32x2 h01 = {bj, 0.0f}, h23 = {0.0f, 0.0f};
#pragma unroll
        for (int ib = 0; ib < 16; ++ib) {
            const float4 rb = *(const float4*)&rowbuf[w][4 * ib];   // broadcast
            const float4 wv = *(const float4*)&wgT[lane][4 * ib];   // own column
            const f32x2 ra = {rb.x, rb.y}, rc = {rb.z, rb.w};
            const f32x2 wa = {wv.x, wv.y}, wc = {wv.z, wv.w};
            h01 += ra * wa;
            h23 += rc * wc;
        }
        float h = (h01.x + h01.y) + (h23.x + h23.y);
        h = h > 0.0f ? h : 0.0f;
        xh[(size_t)n * D + lane] = h;
        s1 += (double)h;
        s2 += (double)h * (double)h;
    }
    // ---- block-level reduce, then 2 atomics per lane-column per block ----
    bn1[w][lane] = s1;
    bn2[w][lane] = s2;
    __syncthreads();
    if (w == 0) {
        atomAdd64(&bnacc[lane], bn1[0][lane] + bn1[1][lane] + bn1[2][lane] + bn1[3][lane]);
        atomAdd64(&bnacc[64 + lane], bn2[0][lane] + bn2[1][lane] + bn2[2][lane] + bn2[3][lane]);
    }
}

// ---- BN finalize ----
__global__ __launch_bounds__(64) void k_bnfin(int layer, const float* __restrict__ gamma,
                                              const float* __restrict__ beta,
                                              const double* __restrict__ bnacc,
                                              double* __restrict__ bnsc) {
    int j = threadIdx.x;
    double mu = bnacc[j] * (1.0 / NN);
    double var = bnacc[64 + j] * (1.0 / NN) - mu * mu;
    double sc = (double)gamma[layer * D + j] / sqrt(var + 1e-5);
    bnsc[j] = sc;
    bnsc[64 + j] = (double)beta[layer * D + j] - mu * sc;
}

// ---- att1 (+fused BN apply): v = bnsc*xh+off -> x32/out; f32 score math ----
template <int LAYER>
__global__ __launch_bounds__(256) void k_att1(const float* __restrict__ xh,
                                              const double* __restrict__ bnsc,
                                              const double* __restrict__ c64,
                                              float* __restrict__ x32,
                                              float* __restrict__ out,
                                              float* __restrict__ scf,
                                              float* __restrict__ bmaxf) {
    const int blk = blockIdx.x, t = threadIdx.x, w = t >> 6, lane = t & 63;
    const int g = blk >> 6;
    __shared__ float wmax[4];
    const float cj = (float)c64[g * D + lane];
    const double bsc = bnsc[lane], boff = bnsc[64 + lane];
    float locmax = -3.0e38f;
    for (int m = 0; m < 16; ++m) {
        const int n = blk * 64 + w * 16 + m;
        const float v32 = (float)(bsc * (double)xh[(size_t)n * D + lane] + boff);
        x32[(size_t)n * D + lane] = v32;
        if (LAYER == NL - 1) out[OUT_X + (size_t)n * D + lane] = v32;
        float v = v32 * cj;
#pragma unroll
        for (int off = 32; off; off >>= 1) v += __shfl_xor(v, off);
        if (lane == 0) scf[n] = v;
        locmax = fmaxf(locmax, v);
    }
    if (lane == 0) wmax[w] = locmax;
    __syncthreads();
    if (t == 0) bmaxf[blk] = fmaxf(fmaxf(wmax[0], wmax[1]), fmaxf(wmax[2], wmax[3]));
}

__global__ __launch_bounds__(64) void k_att2(const float* __restrict__ bmaxf,
                                             float* __restrict__ mxg,
                                             double* __restrict__ num,
                                             double* __restrict__ den) {
    const int g = blockIdx.x, t = threadIdx.x;
    float m = bmaxf[g * 64 + t];
#pragma unroll
    for (int off = 32; off; off >>= 1) m = fmaxf(m, __shfl_xor(m, off));
    if (t == 0) {
        mxg[g] = m;
        den[g] = 0.0;
    }
    num[g * D + t] = 0.0;
}

__global__ __launch_bounds__(256) void k_att3(const float* __restrict__ x32,
                                              const float* __restrict__ scf,
                                              const float* __restrict__ mxg,
                                              double* __restrict__ num,
                                              double* __restrict__ den) {
    const int blk = blockIdx.x, t = threadIdx.x, w = t >> 6, lane = t & 63;
    const int g = blk >> 6;
    __shared__ float cp[4][D];
    __shared__ float wes[4];
    const float mx = mxg[g];
    float accj = 0.0f, esum = 0.0f;
    for (int m = 0; m < 16; ++m) {
        const int n = blk * 64 + w * 16 + m;
        const float e = expf(scf[n] - mx);
        accj += e * x32[(size_t)n * D + lane];
        esum += e;
    }
    cp[w][lane] = accj;
    if (lane == 0) wes[w] = esum;
    __syncthreads();
    if (t < D) {
        atomAdd64(&num[g * D + t], (double)cp[0][t] + (double)cp[1][t] +
                                       (double)cp[2][t] + (double)cp[3][t]);
        if (t == 0)
            atomAdd64(&den[g], (double)wes[0] + (double)wes[1] + (double)wes[2] + (double)wes[3]);
    }
}

__global__ __launch_bounds__(64) void k_att4(const double* __restrict__ num,
                                             const double* __restrict__ den,
                                             double* __restrict__ c64) {
    const int g = blockIdx.x, t = threadIdx.x;
    c64[g * D + t] = num[g * D + t] / den[g];
}

// ---- head: relu(x@W1+b1)@W2+b2, wave-per-row, transposed weights ----
__global__ __launch_bounds__(256) void k_head(const float* __restrict__ x32,
                                              const double* __restrict__ c64,
                                              const float* __restrict__ hW1,
                                              const float* __restrict__ hb1,
                                              const float* __restrict__ hW2,
                                              const float* __restrict__ hb2,
                                              float* __restrict__ out) {
    __shared__ __align__(16) float w1T[D][65];  // w1T[c][i] = W1[i][c]
    __shared__ __align__(16) float w2T[D][65];
    __shared__ __align__(16) float rowb[4][D];
    __shared__ __align__(16) float hrow[4][D];
    const int t = threadIdx.x, w = t >> 6, lane = t & 63;
    for (int idx = t; idx < D * D; idx += 256) {
        const int i = idx >> 6, c = idx & 63;
        w1T[c][i] = hW1[idx];  // idx = i*D + c
        w2T[c][i] = hW2[idx];
    }
    const float b1 = hb1[lane];
    const float b2 = hb2[lane];
    __syncthreads();
    const int ROWS = NN + BSZ;
    const int nwaves = gridDim.x * 4;
    for (int r = blockIdx.x * 4 + w; r < ROWS; r += nwaves) {
        const float xv =
            (r < NN) ? x32[(size_t)r * D + lane] : (float)c64[(size_t)(r - NN) * D + lane];
        rowb[w][lane] = xv;  // same-wave DS in-order
        f32x2 h01 = {b1, 0.0f}, h23 = {0.0f, 0.0f};
#pragma unroll
        for (int ib = 0; ib < 16; ++ib) {
            const float4 rb = *(const float4*)&rowb[w][4 * ib];
            const float4 wv = *(const float4*)&w1T[lane][4 * ib];
            h01 += (f32x2){rb.x, rb.y} * (f32x2){wv.x, wv.y};
            h23 += (f32x2){rb.z, rb.w} * (f32x2){wv.z, wv.w};
        }
        float h = (h01.x + h01.y) + (h23.x + h23.y);
        h = h > 0.f ? h : 0.f;
        hrow[w][lane] = h;  // same-wave DS in-order
        f32x2 o01 = {b2, 0.0f}, o23 = {0.0f, 0.0f};
#pragma unroll
        for (int ib = 0; ib < 16; ++ib) {
            const float4 rb = *(const float4*)&hrow[w][4 * ib];
            const float4 wv = *(const float4*)&w2T[lane][4 * ib];
            o01 += (f32x2){rb.x, rb.y} * (f32x2){wv.x, wv.y};
            o23 += (f32x2){rb.z, rb.w} * (f32x2){wv.z, wv.w};
        }
        const float o = (o01.x + o01.y) + (o23.x + o23.y);
        if (r < NN) {
            out[OUT_XL + (size_t)r * D + lane] = o;
        } else {
            const size_t cr = (size_t)(r - NN) * D + lane;
            out[OUT_CL + cr] = o;
            out[OUT_C + cr] = (float)c64[cr];
        }
    }
}

extern "C" void kernel_launch(void* const* d_in, const int* in_sizes, int n_in,
                              void* d_out, int out_size, void* d_ws, size_t ws_size,
                              hipStream_t stream) {
    const float* xin    = (const float*)d_in[0];
    const int*   ei     = (const int*)d_in[1];
    const float* ewin   = (const float*)d_in[2];
    const float* unoise = (const float*)d_in[5];
    const float* epW1   = (const float*)d_in[6];
    const float* epb1   = (const float*)d_in[7];
    const float* epW2   = (const float*)d_in[8];
    const float* epb2   = (const float*)d_in[9];
    const float* alphap = (const float*)d_in[10];
    const float* ginW   = (const float*)d_in[11];
    const float* ginB   = (const float*)d_in[12];
    const float* bng    = (const float*)d_in[13];
    const float* bnb    = (const float*)d_in[14];
    const float* hW1    = (const float*)d_in[15];
    const float* hb1    = (const float*)d_in[16];
    const float* hW2    = (const float*)d_in[17];
    const float* hb2    = (const float*)d_in[18];
    float* out = (float*)d_out;
    const int* esrc = ei;
    const int* edst = ei + NE;

    char* ws = (char*)d_ws;
    const size_t SZ4 = (size_t)NN * D * sizeof(float);  // 16MB
    // Pb (k_P->k_edge/k_fix) and xh (k_nodeup->k_att1): disjoint live ranges.
    float* Pb32 = (float*)(ws);
    float* xh32 = Pb32;  // alias
    float* Pc32 = (float*)(ws + SZ4);
    float* x32  = (float*)(ws + 2 * SZ4);
    float* ew_csr = (float*)(ws + 3 * SZ4);                       // NE*4 = 4MB
    float* scf  = (float*)(ws + 3 * SZ4 + (size_t)NE * 4);        // NN*4 (slot NN*8)
    char*  p    = ws + 3 * SZ4 + (size_t)NE * 4 + (size_t)NN * 8;
    double* c64  = (double*)p;          p += BSZ * D * 8;
    double* qb   = (double*)p;          p += BSZ * D * 8;
    double* qc   = (double*)p;          p += BSZ * D * 8;
    double* bnacc = (double*)p;         p += 128 * 8;
    double* bnsc  = (double*)p;         p += 128 * 8;
    float*  bmaxf = (float*)p;          p += 1024 * 8;
    float*  mxg   = (float*)p;          p += 16 * 8;
    double* num   = (double*)p;         p += BSZ * D * 8;
    double* den   = (double*)p;         p += 16 * 8;
    // CSR
    int* cnt     = (int*)p;             p += (size_t)NN * 4;
    int* rowptr  = (int*)p;             p += (size_t)(NN + 1) * 4 + 4;
    int* cursor  = (int*)p;             p += (size_t)NN * 4;
    int* bsum    = (int*)p;             p += 256 * 4;
    int* eord    = (int*)p;             p += (size_t)NE * 4;
    int* src_csr = (int*)p;             p += (size_t)NE * 4;
    int* dst_csr = (int*)p;             p += (size_t)NE * 4;
    // near-threshold fixup list
    int* flagcnt  = (int*)p;            p += 8;
    int* flaglist = (int*)p;            p += (size_t)FLAGCAP * 4;

    // ---- CSR build (dst static) ----
    hipMemsetAsync(cnt, 0, (size_t)NN * 4, stream);
    k_deg<<<1024, 256, 0, stream>>>(edst, cnt);
    k_scan1<<<256, 256, 0, stream>>>(cnt, rowptr, bsum);
    k_scan2<<<1, 256, 0, stream>>>(bsum);
    k_scan3<<<256, 256, 0, stream>>>(bsum, rowptr, cursor);
    k_fill<<<1024, 256, 0, stream>>>(esrc, edst, cursor, eord, src_csr, dst_csr);

    hipMemsetAsync(c64, 0, (size_t)BSZ * D * 8, stream);
    k_centroid0<<<BSZ * 8, 256, 0, stream>>>(xin, c64);

    // ---------------- layer 0 ----------------
    k_qbc<<<4, 256, 0, stream>>>(c64, epW1, qb, qc);
    k_P<0><<<2048, 256, 0, stream>>>(xin, x32, epW1, qb, qc, Pb32, Pc32, bnacc);
    hipMemsetAsync(flagcnt, 0, 4, stream);
    k_edge<0><<<2048, 256, 0, stream>>>(xin, src_csr, dst_csr, eord, ewin, ew_csr, unoise,
                                        epW1, epb1, epW2, epb2, alphap, Pb32, Pc32,
                                        flagcnt, flaglist, out);
    k_fix<0><<<64, 256, 0, stream>>>(xin, src_csr, dst_csr, eord, ewin, ew_csr, unoise,
                                     epW1, epb1, epW2, epb2, alphap, Pb32, Pc32,
                                     flagcnt, flaglist, out);
    k_nodeup<0><<<2048, 256, 0, stream>>>(xin, ew_csr, src_csr, rowptr, ginW, ginB,
                                          xh32, bnacc);
    k_bnfin<<<1, 64, 0, stream>>>(0, bng, bnb, bnacc, bnsc);
    k_att1<0><<<1024, 256, 0, stream>>>(xh32, bnsc, c64, x32, out, scf, bmaxf);
    k_att2<<<16, 64, 0, stream>>>(bmaxf, mxg, num, den);
    k_att3<<<1024, 256, 0, stream>>>(x32, scf, mxg, num, den);
    k_att4<<<16, 64, 0, stream>>>(num, den, c64);

    // ---------------- layer 1 ----------------
    k_qbc<<<4, 256, 0, stream>>>(c64, epW1, qb, qc);
    k_P<1><<<2048, 256, 0, stream>>>(xin, x32, epW1, qb, qc, Pb32, Pc32, bnacc);
    hipMemsetAsync(flagcnt, 0, 4, stream);
    k_edge<1><<<2048, 256, 0, stream>>>(x32, src_csr, dst_csr, eord, ewin, ew_csr, unoise,
                                        epW1, epb1, epW2, epb2, alphap, Pb32, Pc32,
                                        flagcnt, flaglist, out);
    k_fix<1><<<64, 256, 0, stream>>>(x32, src_csr, dst_csr, eord, ewin, ew_csr, unoise,
                                     epW1, epb1, epW2, epb2, alphap, Pb32, Pc32,
                                     flagcnt, flaglist, out);
    k_nodeup<1><<<2048, 256, 0, stream>>>(x32, ew_csr, src_csr, rowptr, ginW, ginB,
                                          xh32, bnacc);
    k_bnfin<<<1, 64, 0, stream>>>(1, bng, bnb, bnacc, bnsc);
    k_att1<1><<<1024, 256, 0, stream>>>(xh32, bnsc, c64, x32, out, scf, bmaxf);
    k_att2<<<16, 64, 0, stream>>>(bmaxf, mxg, num, den);
    k_att3<<<1024, 256, 0, stream>>>(x32, scf, mxg, num, den);
    k_att4<<<16, 64, 0, stream>>>(num, den, c64);

    // ---------------- heads + centroid output ----------------
    k_head<<<2048, 256, 0, stream>>>(x32, c64, hW1, hb1, hW2, hb2, out);
}

// Round 19
// 775.279 us; speedup vs baseline: 1.2582x; 1.0147x over previous
//
#include <hip/hip_runtime.h>
#include <hip/hip_bf16.h>

// GraphCAD forward on MI355X. All float I/O is f32.
// R25->R26: launch-graph consolidation, bit-identical math. (1) k_bnfin
// folded into k_att1 (each thread computes bsc/boff from bnacc+gamma/beta,
// same f64 formula). (2) k_att4 deleted: centroid kept as double-buffered
// (cnum,cden); every consumer does the same f64 division cnum/cden att4
// would have done (centroid0 writes (sum,NPG) to buf0; layer l reads
// buf[l], att3 accumulates buf[l^1]; head reads buf0). (3) k_att2 deleted:
// att3 computes mxg inline (wave reduce of bmaxf); next-buffer zeroing in
// att1 block 0 (kernel-boundary ordered vs att3 atomics). 6 launches
// removed. k_edge/k_fix/k_nodeup/k_P/qbc/CSR/head math byte-identical to
// R25 (786.7us).

#define D 64
#define BSZ 16
#define NPG 4096
#define NN (BSZ * NPG)   // 65536 nodes
#define NE (NN * 16)     // 1048576 edges
#define NL 2
#define NTILE (NE / 64)  // 16384

#define FIXTH 2e-3f
#define FLAGCAP 65536

// output layout (elements, f32)
#define OUT_X  0u
#define OUT_EW 4194304u
#define OUT_C  5242880u
#define OUT_XL 5243904u
#define OUT_CL 9438208u
#define OUT_PA 9439232u

typedef __attribute__((ext_vector_type(2))) float f32x2;

__device__ __forceinline__ void atomAdd64(double* p, double v) { unsafeAtomicAdd(p, v); }

// ================= CSR build (dst is a static input; rebuilt per call) ======
__global__ __launch_bounds__(256) void k_deg(const int* __restrict__ edst,
                                             int* __restrict__ cnt) {
    int stride = gridDim.x * 256;
    for (int e = blockIdx.x * 256 + threadIdx.x; e < NE; e += stride)
        atomicAdd(&cnt[edst[e]], 1);
}

__global__ __launch_bounds__(256) void k_scan1(const int* __restrict__ cnt,
                                               int* __restrict__ rowptr,
                                               int* __restrict__ bsum) {
    __shared__ int sd[256];
    const int b = blockIdx.x, t = threadIdx.x;
    const int v = cnt[b * 256 + t];
    sd[t] = v;
    __syncthreads();
    for (int off = 1; off < 256; off <<= 1) {
        int tmp = (t >= off) ? sd[t - off] : 0;
        __syncthreads();
        sd[t] += tmp;
        __syncthreads();
    }
    rowptr[b * 256 + t] = sd[t] - v;  // exclusive
    if (t == 255) bsum[b] = sd[255];
}

__global__ __launch_bounds__(256) void k_scan2(int* __restrict__ bsum) {
    __shared__ int sd[256];
    const int t = threadIdx.x;
    const int v = bsum[t];
    sd[t] = v;
    __syncthreads();
    for (int off = 1; off < 256; off <<= 1) {
        int tmp = (t >= off) ? sd[t - off] : 0;
        __syncthreads();
        sd[t] += tmp;
        __syncthreads();
    }
    bsum[t] = sd[t] - v;  // exclusive
}

__global__ __launch_bounds__(256) void k_scan3(const int* __restrict__ bsum,
                                               int* __restrict__ rowptr,
                                               int* __restrict__ cursor) {
    const int i = blockIdx.x * 256 + threadIdx.x;
    const int r = rowptr[i] + bsum[blockIdx.x];
    rowptr[i] = r;
    cursor[i] = r;
    if (i == 0) rowptr[NN] = NE;
}

// fill CSR: slot -> original edge (eord), src (src_csr), dst (dst_csr).
__global__ __launch_bounds__(256) void k_fill(const int* __restrict__ esrc,
                                              const int* __restrict__ edst,
                                              int* __restrict__ cursor,
                                              int* __restrict__ eord,
                                              int* __restrict__ src_csr,
                                              int* __restrict__ dst_csr) {
    int stride = gridDim.x * 256;
    for (int e = blockIdx.x * 256 + threadIdx.x; e < NE; e += stride) {
        const int d = edst[e];
        int pos = atomicAdd(&cursor[d], 1);
        eord[pos] = e;
        src_csr[pos] = esrc[e];
        dst_csr[pos] = d;
    }
}

// ---- initial centroid: per-graph SUM of x into cnum0, cden0 = NPG ----
__global__ __launch_bounds__(256) void k_centroid0(const float* __restrict__ xin,
                                                   double* __restrict__ cnum0,
                                                   double* __restrict__ cden0) {
    const int g = blockIdx.x >> 3, sub = blockIdx.x & 7, tid = threadIdx.x;
    const int r = tid >> 6, f = tid & 63;
    __shared__ double cr[4][D];
    double s = 0.0;
    for (int k = 0; k < NPG / 8 / 4; ++k) {
        size_t n = (size_t)g * NPG + (size_t)(sub * (NPG / 8) + 4 * k + r);
        s += (double)xin[n * D + f];
    }
    cr[r][f] = s;
    __syncthreads();
    if (tid < D)
        atomAdd64(&cnum0[g * D + tid],
                  (cr[0][tid] + cr[1][tid] + cr[2][tid] + cr[3][tid]) * (1.0 / NPG));
    if (sub == 0 && tid == 0) cden0[g] = 1.0;  // cnum0 already holds the mean
}

// ---- qb = c @ W1b, qc = c @ W1c (per graph, f64); c = cnum/cden ----
__global__ __launch_bounds__(256) void k_qbc(const double* __restrict__ cnum,
                                             const double* __restrict__ cden,
                                             const float* __restrict__ epW1,
                                             double* __restrict__ qb, double* __restrict__ qc) {
    int gj = blockIdx.x * 256 + threadIdx.x;
    if (gj >= BSZ * D) return;
    int g = gj >> 6, j = gj & 63;
    const double dn = cden[g];
    double sb = 0.0, sc = 0.0;
#pragma unroll
    for (int i = 0; i < D; ++i) {
        double cv = cnum[g * D + i] / dn;
        sb += cv * (double)epW1[(D + i) * D + j];
        sc += cv * (double)epW1[(2 * D + i) * D + j];
    }
    qb[gj] = sb;
    qc[gj] = sc;
}

// ---- P'_b = x@W1b - qb[g], P'_c = x@W1c - qc[g]; f32, wave-per-node ----
template <int LAYER>
__global__ __launch_bounds__(256) void k_P(const float* __restrict__ xin,
                                           const float* __restrict__ x32,
                                           const float* __restrict__ epW1,
                                           const double* __restrict__ qb,
                                           const double* __restrict__ qc,
                                           float* __restrict__ Pb, float* __restrict__ Pc,
                                           double* __restrict__ bnacc) {
    if (blockIdx.x == 0 && threadIdx.x < 128) bnacc[threadIdx.x] = 0.0;
    __shared__ __align__(16) float wbT[D][65];  // wbT[c][i] = W1b[i][c]
    __shared__ __align__(16) float wcT[D][65];
    __shared__ __align__(16) float rowbuf[4][D];
    const int t = threadIdx.x, w = t >> 6, lane = t & 63;
    for (int idx = t; idx < D * D; idx += 256) {
        const int i = idx >> 6, c = idx & 63;
        wbT[c][i] = epW1[(D + i) * D + c];
        wcT[c][i] = epW1[(2 * D + i) * D + c];
    }
    __syncthreads();
    const int nwaves = gridDim.x * 4;
    for (int n = blockIdx.x * 4 + w; n < NN; n += nwaves) {
        const float xv = (LAYER == 0) ? xin[(size_t)n * D + lane] : x32[(size_t)n * D + lane];
        rowbuf[w][lane] = xv;  // same-wave DS in-order
        f32x2 pb2 = {0.0f, 0.0f}, pc2 = {0.0f, 0.0f};
#pragma unroll
        for (int ib = 0; ib < 16; ++ib) {
            const float4 rb = *(const float4*)&rowbuf[w][4 * ib];   // broadcast
            const float4 wbv = *(const float4*)&wbT[lane][4 * ib];  // own column
            const float4 wcv = *(const float4*)&wcT[lane][4 * ib];
            const f32x2 ra = {rb.x, rb.y}, rc = {rb.z, rb.w};
            const f32x2 wb01 = {wbv.x, wbv.y}, wb23 = {wbv.z, wbv.w};
            const f32x2 wc01 = {wcv.x, wcv.y}, wc23 = {wcv.z, wcv.w};
            pb2 += ra * wb01;
            pb2 += rc * wb23;
            pc2 += ra * wc01;
            pc2 += rc * wc23;
        }
        const int g = n >> 12;
        Pb[(size_t)n * D + lane] = (pb2.x + pb2.y) - (float)qb[g * D + lane];
        Pc[(size_t)n * D + lane] = (pc2.x + pc2.y) - (float)qc[g * D + lane];
    }
}

// ---- edge scorer, CSR order: all-f32 tile GEMM (packed f32x2 acc) ----
template <int LAYER>
__global__ __launch_bounds__(256, 4) void k_edge(const float* __restrict__ xsrc,
                                                 const int* __restrict__ src_csr,
                                                 const int* __restrict__ dst_csr,
                                                 const int* __restrict__ eord,
                                                 const float* __restrict__ ewin,
                                                 float* __restrict__ ew_csr,
                                                 const float* __restrict__ unoise,
                                                 const float* __restrict__ epW1,
                                                 const float* __restrict__ epb1,
                                                 const float* __restrict__ epW2,
                                                 const float* __restrict__ epb2,
                                                 const float* __restrict__ alphap,
                                                 const float* __restrict__ Pb32,
                                                 const float* __restrict__ Pc32,
                                                 int* __restrict__ flagcnt,
                                                 int* __restrict__ flaglist,
                                                 float* __restrict__ out) {
    const int t = threadIdx.x;
    const int tx = t & 15, ty = t >> 4;

    __shared__ __align__(16) float ldsA[64 * 64];  // |dx| [dim][slot]
    __shared__ __align__(16) float ldsW[64 * 64];  // W1a [k][j]

    for (int idx = t; idx < D * D; idx += 256) {
        ldsW[idx] = epW1[idx];  // [k][j] layout matches epW1 row-major
    }
    float b1f[4], w2f[4];
#pragma unroll
    for (int c = 0; c < 4; ++c) {
        b1f[c] = epb1[4 * tx + c];
        w2f[c] = epW2[4 * tx + c];
    }
    const float b2v = epb2[0];
    const float alpha = alphap[0];
    __syncthreads();

    const int eloc = t >> 2, q = t & 3;

    for (int tile = blockIdx.x; tile < NTILE; tile += gridDim.x) {
        const int base = tile * 64;

        // ---- stage |x_d - x_s| (f32, transposed). d-rows run-repeat (L1). --
        {
            const int pos = base + eloc;
            const int s = src_csr[pos], d = dst_csr[pos];
            const float* rs = xsrc + (size_t)s * D + q * 16;
            const float* rd = xsrc + (size_t)d * D + q * 16;
#pragma unroll
            for (int c = 0; c < 4; ++c) {
                const float4 fd = *(const float4*)(rd + 4 * c);
                const float4 fs = *(const float4*)(rs + 4 * c);
                const int dim = q * 16 + 4 * c;
                ldsA[(dim + 0) * 64 + eloc] = fabsf(fd.x - fs.x);
                ldsA[(dim + 1) * 64 + eloc] = fabsf(fd.y - fs.y);
                ldsA[(dim + 2) * 64 + eloc] = fabsf(fd.z - fs.z);
                ldsA[(dim + 3) * 64 + eloc] = fabsf(fd.w - fs.w);
            }
        }
        __syncthreads();

        // ---- 64x64x64 GEMM: f32 inputs, packed f32x2 accumulate ----
        f32x2 acc2[4][2];
#pragma unroll
        for (int r = 0; r < 4; ++r)
#pragma unroll
            for (int c = 0; c < 2; ++c) {
                f32x2 z = {0.0f, 0.0f};
                acc2[r][c] = z;
            }

#pragma unroll 4
        for (int k = 0; k < 64; ++k) {
            const float4 af = *(const float4*)&ldsA[k * 64 + 4 * ty];
            const float4 wf = *(const float4*)&ldsW[k * 64 + 4 * tx];
            const f32x2 w01 = {wf.x, wf.y};
            const f32x2 w23 = {wf.z, wf.w};
            const float av[4] = {af.x, af.y, af.z, af.w};
#pragma unroll
            for (int r = 0; r < 4; ++r) {
                const f32x2 avv = {av[r], av[r]};
                acc2[r][0] += avv * w01;  // -> v_pk_fma_f32
                acc2[r][1] += avv * w23;
            }
        }
        __syncthreads();  // A dead -> reuse as f32 sred

        float* sred = ldsA;
        // ---- epilogue: + P' terms, +b1, relu, * w2, partial sums ----
#pragma unroll
        for (int r = 0; r < 4; ++r) {
            const int pos = base + 4 * ty + r;
            const int s = src_csr[pos], d = dst_csr[pos];
            const float4 pb = *(const float4*)(Pb32 + (size_t)d * D + 4 * tx);
            const float4 pc = *(const float4*)(Pc32 + (size_t)s * D + 4 * tx);
            float part = 0.0f;
            float h;
            h = acc2[r][0].x + pb.x + pc.x + b1f[0];
            if (h > 0.0f) part += h * w2f[0];
            h = acc2[r][0].y + pb.y + pc.y + b1f[1];
            if (h > 0.0f) part += h * w2f[1];
            h = acc2[r][1].x + pb.z + pc.z + b1f[2];
            if (h > 0.0f) part += h * w2f[2];
            h = acc2[r][1].y + pb.w + pc.w + b1f[3];
            if (h > 0.0f) part += h * w2f[3];
            sred[(4 * ty + r) * 17 + tx] = part;
        }
        __syncthreads();

        // ---- score reduce + RelaxedBernoulli sample (one lane per slot) ----
        if (t < 64) {
            float sc_ = b2v;
#pragma unroll
            for (int i = 0; i < 16; ++i) sc_ += sred[t * 17 + i];
            const int pos = base + t;
            const int e = eord[pos];
            const float u = unoise[(size_t)LAYER * NE + e];
            const float gn = logf(u) - log1pf(-u);
            const float mar = sc_ + gn;  // decision margin; samp == (mar > 0)
            bool deferred = false;
            if (fabsf(mar) < FIXTH) {
                int slot = atomicAdd(flagcnt, 1);
                if (slot < FLAGCAP) {
                    flaglist[slot] = pos;
                    deferred = true;  // k_fix decides + writes this edge
                }
            }
            if (!deferred) {
                const float pre = 1.0f / (1.0f + expf(-sc_));
                const bool samp = mar > 0.0f;
                const float ewo = (LAYER == 0) ? ewin[e] : ew_csr[pos];
                const float ewn = samp ? alpha * ewo + (1.0f - alpha) * pre : 0.0f;
                ew_csr[pos] = ewn;
                if (LAYER == NL - 1) {
                    out[OUT_EW + (size_t)e] = ewn;
                    out[OUT_PA + (size_t)e] = pre;
                }
            }
        }
        __syncthreads();
    }
}

// ---- exact f64 re-decision for near-threshold edges (one wave per edge) ----
template <int LAYER>
__global__ __launch_bounds__(256) void k_fix(const float* __restrict__ xsrc,
                                             const int* __restrict__ src_csr,
                                             const int* __restrict__ dst_csr,
                                             const int* __restrict__ eord,
                                             const float* __restrict__ ewin,
                                             float* __restrict__ ew_csr,
                                             const float* __restrict__ unoise,
                                             const float* __restrict__ epW1,
                                             const float* __restrict__ epb1,
                                             const float* __restrict__ epW2,
                                             const float* __restrict__ epb2,
                                             const float* __restrict__ alphap,
                                             const float* __restrict__ Pb32,
                                             const float* __restrict__ Pc32,
                                             const int* __restrict__ flagcnt,
                                             const int* __restrict__ flaglist,
                                             float* __restrict__ out) {
    const int n = min(flagcnt[0], FLAGCAP);
    __shared__ float dxs[4][D];
    const int w = threadIdx.x >> 6, lane = threadIdx.x & 63;
    const int nw = gridDim.x * 4;
    for (int i = blockIdx.x * 4 + w; i < n; i += nw) {
        const int pos = flaglist[i];
        const int s = src_csr[pos], d = dst_csr[pos];
        // |dx| from the same f32 inputs the main kernel staged
        dxs[w][lane] = fabsf(xsrc[(size_t)d * D + lane] - xsrc[(size_t)s * D + lane]);
        // wave-internal broadcast (same-wave DS in-order)
        double h = 0.0;
#pragma unroll
        for (int k = 0; k < D; ++k) h += (double)dxs[w][k] * (double)epW1[k * D + lane];
        h += (double)Pb32[(size_t)d * D + lane] + (double)Pc32[(size_t)s * D + lane] +
             (double)epb1[lane];
        double part = (h > 0.0) ? h * (double)epW2[lane] : 0.0;
#pragma unroll
        for (int off = 32; off; off >>= 1) part += __shfl_xor(part, off);
        if (lane == 0) {
            const double sc_ = part + (double)epb2[0];
            const int e = eord[pos];
            const double u = (double)unoise[(size_t)LAYER * NE + e];
            const double gn = log(u) - log1p(-u);
            const double pre = 1.0 / (1.0 + exp(-sc_));
            const bool samp = (sc_ + gn) > 0.0;
            const double ewo = (LAYER == 0) ? (double)ewin[e] : (double)ew_csr[pos];
            const double alpha = (double)alphap[0];
            const double ewn = samp ? alpha * ewo + (1.0 - alpha) * pre : 0.0;
            ew_csr[pos] = (float)ewn;
            if (LAYER == NL - 1) {
                out[OUT_EW + (size_t)e] = (float)ewn;
                out[OUT_PA + (size_t)e] = (float)pre;
            }
        }
    }
}

// ---- node update: CSR gather (row-parallel loads) + GIN mlp + BN partials --
template <int LAYER>
__global__ __launch_bounds__(256) void k_nodeup(const float* __restrict__ xsrc,
                                                const float* __restrict__ ew_csr,
                                                const int* __restrict__ src_csr,
                                                const int* __restrict__ rowptr,
                                                const float* __restrict__ ginW,
                                                const float* __restrict__ ginB,
                                                float* __restrict__ xh,
                                                double* __restrict__ bnacc) {
    __shared__ __align__(16) float wgT[D][65];  // wgT[c][i] = W[i][c]
    __shared__ __align__(16) float rowbuf[4][D];
    __shared__ double bn1[4][D];
    __shared__ double bn2[4][D];
    const int t = threadIdx.x, w = t >> 6, lane = t & 63;
    const int e = lane >> 4, q = lane & 15;  // slot, quarter (dims 4q..4q+3)
    for (int idx = t; idx < D * D; idx += 256) {
        const int i = idx >> 6, c = idx & 63;
        wgT[c][i] = ginW[LAYER * D * D + idx];  // idx = i*D + c
    }
    const float bj = ginB[LAYER * D + lane];
    __syncthreads();
    double s1 = 0.0, s2 = 0.0;
    const int nwaves = gridDim.x * 4;
    for (int n = blockIdx.x * 4 + w; n < NN; n += nwaves) {
        const int rs = rowptr[n], re = rowptr[n + 1];
        const int deg = re - rs;
        // ---- first 16 edges: 4 masked slots x 4 chunks, all loads up front
        const int i0 = rs + ((e < deg) ? e : 0);
        const int i1 = rs + ((4 + e < deg) ? 4 + e : 0);
        const int i2 = rs + ((8 + e < deg) ? 8 + e : 0);
        const int i3 = rs + ((12 + e < deg) ? 12 + e : 0);
        const float w0 = (e < deg) ? ew_csr[i0] : 0.f;
        const float w1 = (4 + e < deg) ? ew_csr[i1] : 0.f;
        const float w2 = (8 + e < deg) ? ew_csr[i2] : 0.f;
        const float w3 = (12 + e < deg) ? ew_csr[i3] : 0.f;
        const int s0 = src_csr[i0], s1_ = src_csr[i1];
        const int s2_ = src_csr[i2], s3_ = src_csr[i3];
        const float4 r0 = *(const float4*)(xsrc + (size_t)s0 * D + 4 * q);
        const float4 r1 = *(const float4*)(xsrc + (size_t)s1_ * D + 4 * q);
        const float4 r2 = *(const float4*)(xsrc + (size_t)s2_ * D + 4 * q);
        const float4 r3 = *(const float4*)(xsrc + (size_t)s3_ * D + 4 * q);
        const float4 rf = *(const float4*)(xsrc + (size_t)n * D + 4 * q);  // self
        f32x2 a01, a23;
        {
            const f32x2 w0v = {w0, w0}, w1v = {w1, w1}, w2v = {w2, w2}, w3v = {w3, w3};
            const f32x2 r0a = {r0.x, r0.y}, r0b = {r0.z, r0.w};
            const f32x2 r1a = {r1.x, r1.y}, r1b = {r1.z, r1.w};
            const f32x2 r2a = {r2.x, r2.y}, r2b = {r2.z, r2.w};
            const f32x2 r3a = {r3.x, r3.y}, r3b = {r3.z, r3.w};
            a01 = w0v * r0a;
            a23 = w0v * r0b;
            a01 += w1v * r1a;
            a23 += w1v * r1b;
            a01 += w2v * r2a;
            a23 += w2v * r2b;
            a01 += w3v * r3a;
            a23 += w3v * r3b;
        }
        // ---- tail: edges beyond 16, masked chunks of 4 (wave-uniform bound)
        for (int k = rs + 16; k < re; k += 4) {
            const int kk = k + e;
            const bool v = kk < re;
            const float wt = v ? ew_csr[kk] : 0.f;
            const int st = src_csr[v ? kk : rs];
            const float4 rt = *(const float4*)(xsrc + (size_t)st * D + 4 * q);
            const f32x2 wtv = {wt, wt};
            const f32x2 rta = {rt.x, rt.y}, rtb = {rt.z, rt.w};
            a01 += wtv * rta;
            a23 += wtv * rtb;
        }
        float a0 = a01.x, a1 = a01.y, a2 = a23.x, a3 = a23.y;
        // ---- tree-reduce the 4 slots (lanes differing in bits 4,5) ----
        a0 += __shfl_xor(a0, 16);
        a1 += __shfl_xor(a1, 16);
        a2 += __shfl_xor(a2, 16);
        a3 += __shfl_xor(a3, 16);
        a0 += __shfl_xor(a0, 32);
        a1 += __shfl_xor(a1, 32);
        a2 += __shfl_xor(a2, 32);
        a3 += __shfl_xor(a3, 32);
        // ---- + self, publish to rowbuf (same-wave DS in-order) ----
        if (e == 0) {
            rowbuf[w][4 * q + 0] = a0 + rf.x;
            rowbuf[w][4 * q + 1] = a1 + rf.y;
            rowbuf[w][4 * q + 2] = a2 + rf.z;
            rowbuf[w][4 * q + 3] = a3 + rf.w;
        }
        // ---- GIN matvec (packed f32, transposed weights) ----
        f32x2 h01 = {bj, 0.0f}, h23 = {0.0f, 0.0f};
#pragma unroll
        for (int ib = 0; ib < 16; ++ib) {
            const float4 rb = *(const float4*)&rowbuf[w][4 * ib];   // broadcast
            const float4 wv = *(const float4*)&wgT[lane][4 * ib];   // own column
            const f32x2 ra = {rb.x, rb.y}, rc = {rb.z, rb.w};
            const f32x2 wa = {wv.x, wv.y}, wc = {wv.z, wv.w};
            h01 += ra * wa;
            h23 += rc * wc;
        }
        float h = (h01.x + h01.y) + (h23.x + h23.y);
        h = h > 0.0f ? h : 0.0f;
        xh[(size_t)n * D + lane] = h;
        s1 += (double)h;
        s2 += (double)h * (double)h;
    }
    // ---- block-level reduce, then 2 atomics per lane-column per block ----
    bn1[w][lane] = s1;
    bn2[w][lane] = s2;
    __syncthreads();
    if (w == 0) {
        atomAdd64(&bnacc[lane], bn1[0][lane] + bn1[1][lane] + bn1[2][lane] + bn1[3][lane]);
        atomAdd64(&bnacc[64 + lane], bn2[0][lane] + bn2[1][lane] + bn2[2][lane] + bn2[3][lane]);
    }
}

// ---- att1 (+fused bnfin + BN apply): v = bsc*xh+boff -> x32/out; score ----
// Also zeroes the NEXT centroid buffers (block 0) for att3's accumulation.
template <int LAYER>
__global__ __launch_bounds__(256) void k_att1(const float* __restrict__ xh,
                                              const double* __restrict__ bnacc,
                                              const float* __restrict__ bng,
                                              const float* __restrict__ bnb,
                                              const double* __restrict__ cnum,
                                              const double* __restrict__ cden,
                                              double* __restrict__ nxtNum,
                                              double* __restrict__ nxtDen,
                                              float* __restrict__ x32,
                                              float* __restrict__ out,
                                              float* __restrict__ scf,
                                              float* __restrict__ bmaxf) {
    const int blk = blockIdx.x, t = threadIdx.x, w = t >> 6, lane = t & 63;
    const int g = blk >> 6;
    if (blk == 0) {  // zero next-layer centroid accumulators (pre-att3)
        for (int i = t; i < BSZ * D; i += 256) nxtNum[i] = 0.0;
        if (t < BSZ) nxtDen[t] = 0.0;
    }
    __shared__ float wmax[4];
    const float cj = (float)(cnum[g * D + lane] / cden[g]);
    // bnfin inlined (same f64 formula as the old k_bnfin kernel):
    const double mu = bnacc[lane] * (1.0 / NN);
    const double var = bnacc[64 + lane] * (1.0 / NN) - mu * mu;
    const double bsc = (double)bng[LAYER * D + lane] / sqrt(var + 1e-5);
    const double boff = (double)bnb[LAYER * D + lane] - mu * bsc;
    float locmax = -3.0e38f;
    for (int m = 0; m < 16; ++m) {
        const int n = blk * 64 + w * 16 + m;
        const float v32 = (float)(bsc * (double)xh[(size_t)n * D + lane] + boff);
        x32[(size_t)n * D + lane] = v32;
        if (LAYER == NL - 1) out[OUT_X + (size_t)n * D + lane] = v32;
        float v = v32 * cj;
#pragma unroll
        for (int off = 32; off; off >>= 1) v += __shfl_xor(v, off);
        if (lane == 0) scf[n] = v;
        locmax = fmaxf(locmax, v);
    }
    if (lane == 0) wmax[w] = locmax;
    __syncthreads();
    if (t == 0) bmaxf[blk] = fmaxf(fmaxf(wmax[0], wmax[1]), fmaxf(wmax[2], wmax[3]));
}

// ---- att3 (+inline mxg reduce): accumulate next centroid (num,den) ----
__global__ __launch_bounds__(256) void k_att3(const float* __restrict__ x32,
                                              const float* __restrict__ scf,
                                              const float* __restrict__ bmaxf,
                                              double* __restrict__ accNum,
                                              double* __restrict__ accDen) {
    const int blk = blockIdx.x, t = threadIdx.x, w = t >> 6, lane = t & 63;
    const int g = blk >> 6;
    __shared__ float cp[4][D];
    __shared__ float wes[4];
    __shared__ float mxsh;
    if (t < 64) {  // inline mxg: max over this graph's 64 block maxima
        float m = bmaxf[g * 64 + t];
#pragma unroll
        for (int off = 32; off; off >>= 1) m = fmaxf(m, __shfl_xor(m, off));
        if (t == 0) mxsh = m;
    }
    __syncthreads();
    const float mx = mxsh;
    float accj = 0.0f, esum = 0.0f;
    for (int m = 0; m < 16; ++m) {
        const int n = blk * 64 + w * 16 + m;
        const float e = expf(scf[n] - mx);
        accj += e * x32[(size_t)n * D + lane];
        esum += e;
    }
    cp[w][lane] = accj;
    if (lane == 0) wes[w] = esum;
    __syncthreads();
    if (t < D) {
        atomAdd64(&accNum[g * D + t], (double)cp[0][t] + (double)cp[1][t] +
                                          (double)cp[2][t] + (double)cp[3][t]);
        if (t == 0)
            atomAdd64(&accDen[g],
                      (double)wes[0] + (double)wes[1] + (double)wes[2] + (double)wes[3]);
    }
}

// ---- head: relu(x@W1+b1)@W2+b2, wave-per-row; centroid = cnum/cden ----
__global__ __launch_bounds__(256) void k_head(const float* __restrict__ x32,
                                              const double* __restrict__ cnum,
                                              const double* __restrict__ cden,
                                              const float* __restrict__ hW1,
                                              const float* __restrict__ hb1,
                                              const float* __restrict__ hW2,
                                              const float* __restrict__ hb2,
                                              float* __restrict__ out) {
    __shared__ __align__(16) float w1T[D][65];  // w1T[c][i] = W1[i][c]
    __shared__ __align__(16) float w2T[D][65];
    __shared__ __align__(16) float rowb[4][D];
    __shared__ __align__(16) float hrow[4][D];
    const int t = threadIdx.x, w = t >> 6, lane = t & 63;
    for (int idx = t; idx < D * D; idx += 256) {
        const int i = idx >> 6, c = idx & 63;
        w1T[c][i] = hW1[idx];  // idx = i*D + c
        w2T[c][i] = hW2[idx];
    }
    const float b1 = hb1[lane];
    const float b2 = hb2[lane];
    __syncthreads();
    const int ROWS = NN + BSZ;
    const int nwaves = gridDim.x * 4;
    for (int r = blockIdx.x * 4 + w; r < ROWS; r += nwaves) {
        double cv = 0.0;
        float xv;
        if (r < NN) {
            xv = x32[(size_t)r * D + lane];
        } else {
            const int g = r - NN;
            cv = cnum[(size_t)g * D + lane] / cden[g];
            xv = (float)cv;
        }
        rowb[w][lane] = xv;  // same-wave DS in-order
        f32x2 h01 = {b1, 0.0f}, h23 = {0.0f, 0.0f};
#pragma unroll
        for (int ib = 0; ib < 16; ++ib) {
            const float4 rb = *(const float4*)&rowb[w][4 * ib];
            const float4 wv = *(const float4*)&w1T[lane][4 * ib];
            h01 += (f32x2){rb.x, rb.y} * (f32x2){wv.x, wv.y};
            h23 += (f32x2){rb.z, rb.w} * (f32x2){wv.z, wv.w};
        }
        float h = (h01.x + h01.y) + (h23.x + h23.y);
        h = h > 0.f ? h : 0.f;
        hrow[w][lane] = h;  // same-wave DS in-order
        f32x2 o01 = {b2, 0.0f}, o23 = {0.0f, 0.0f};
#pragma unroll
        for (int ib = 0; ib < 16; ++ib) {
            const float4 rb = *(const float4*)&hrow[w][4 * ib];
            const float4 wv = *(const float4*)&w2T[lane][4 * ib];
            o01 += (f32x2){rb.x, rb.y} * (f32x2){wv.x, wv.y};
            o23 += (f32x2){rb.z, rb.w} * (f32x2){wv.z, wv.w};
        }
        const float o = (o01.x + o01.y) + (o23.x + o23.y);
        if (r < NN) {
            out[OUT_XL + (size_t)r * D + lane] = o;
        } else {
            const size_t cr = (size_t)(r - NN) * D + lane;
            out[OUT_CL + cr] = o;
            out[OUT_C + cr] = (float)cv;
        }
    }
}

extern "C" void kernel_launch(void* const* d_in, const int* in_sizes, int n_in,
                              void* d_out, int out_size, void* d_ws, size_t ws_size,
                              hipStream_t stream) {
    const float* xin    = (const float*)d_in[0];
    const int*   ei     = (const int*)d_in[1];
    const float* ewin   = (const float*)d_in[2];
    const float* unoise = (const float*)d_in[5];
    const float* epW1   = (const float*)d_in[6];
    const float* epb1   = (const float*)d_in[7];
    const float* epW2   = (const float*)d_in[8];
    const float* epb2   = (const float*)d_in[9];
    const float* alphap = (const float*)d_in[10];
    const float* ginW   = (const float*)d_in[11];
    const float* ginB   = (const float*)d_in[12];
    const float* bng    = (const float*)d_in[13];
    const float* bnb    = (const float*)d_in[14];
    const float* hW1    = (const float*)d_in[15];
    const float* hb1    = (const float*)d_in[16];
    const float* hW2    = (const float*)d_in[17];
    const float* hb2    = (const float*)d_in[18];
    float* out = (float*)d_out;
    const int* esrc = ei;
    const int* edst = ei + NE;

    char* ws = (char*)d_ws;
    const size_t SZ4 = (size_t)NN * D * sizeof(float);  // 16MB
    // Pb (k_P->k_edge/k_fix) and xh (k_nodeup->k_att1): disjoint live ranges.
    float* Pb32 = (float*)(ws);
    float* xh32 = Pb32;  // alias
    float* Pc32 = (float*)(ws + SZ4);
    float* x32  = (float*)(ws + 2 * SZ4);
    float* ew_csr = (float*)(ws + 3 * SZ4);                       // NE*4 = 4MB
    float* scf  = (float*)(ws + 3 * SZ4 + (size_t)NE * 4);        // NN*4 (slot NN*8)
    char*  p    = ws + 3 * SZ4 + (size_t)NE * 4 + (size_t)NN * 8;
    double* cnum = (double*)p;          p += 2 * BSZ * D * 8;     // [2] buffers
    double* cden = (double*)p;          p += 2 * BSZ * 8;
    double* qb   = (double*)p;          p += BSZ * D * 8;
    double* qc   = (double*)p;          p += BSZ * D * 8;
    double* bnacc = (double*)p;         p += 128 * 8;
    float*  bmaxf = (float*)p;          p += 1024 * 8;
    // CSR
    int* cnt     = (int*)p;             p += (size_t)NN * 4;
    int* rowptr  = (int*)p;             p += (size_t)(NN + 1) * 4 + 4;
    int* cursor  = (int*)p;             p += (size_t)NN * 4;
    int* bsum    = (int*)p;             p += 256 * 4;
    int* eord    = (int*)p;             p += (size_t)NE * 4;
    int* src_csr = (int*)p;             p += (size_t)NE * 4;
    int* dst_csr = (int*)p;             p += (size_t)NE * 4;
    // near-threshold fixup list
    int* flagcnt  = (int*)p;            p += 8;
    int* flaglist = (int*)p;            p += (size_t)FLAGCAP * 4;

    double* cnum0 = cnum;
    double* cnum1 = cnum + BSZ * D;
    double* cden0 = cden;
    double* cden1 = cden + BSZ;

    // ---- CSR build (dst static) ----
    hipMemsetAsync(cnt, 0, (size_t)NN * 4, stream);
    k_deg<<<1024, 256, 0, stream>>>(edst, cnt);
    k_scan1<<<256, 256, 0, stream>>>(cnt, rowptr, bsum);
    k_scan2<<<1, 256, 0, stream>>>(bsum);
    k_scan3<<<256, 256, 0, stream>>>(bsum, rowptr, cursor);
    k_fill<<<1024, 256, 0, stream>>>(esrc, edst, cursor, eord, src_csr, dst_csr);

    hipMemsetAsync(cnum0, 0, (size_t)BSZ * D * 8, stream);
    k_centroid0<<<BSZ * 8, 256, 0, stream>>>(xin, cnum0, cden0);

    // ---------------- layer 0 (centroid buf0 -> accumulate buf1) ----------
    k_qbc<<<4, 256, 0, stream>>>(cnum0, cden0, epW1, qb, qc);
    k_P<0><<<2048, 256, 0, stream>>>(xin, x32, epW1, qb, qc, Pb32, Pc32, bnacc);
    hipMemsetAsync(flagcnt, 0, 4, stream);
    k_edge<0><<<2048, 256, 0, stream>>>(xin, src_csr, dst_csr, eord, ewin, ew_csr, unoise,
                                        epW1, epb1, epW2, epb2, alphap, Pb32, Pc32,
                                        flagcnt, flaglist, out);
    k_fix<0><<<64, 256, 0, stream>>>(xin, src_csr, dst_csr, eord, ewin, ew_csr, unoise,
                                     epW1, epb1, epW2, epb2, alphap, Pb32, Pc32,
                                     flagcnt, flaglist, out);
    k_nodeup<0><<<2048, 256, 0, stream>>>(xin, ew_csr, src_csr, rowptr, ginW, ginB,
                                          xh32, bnacc);
    k_att1<0><<<1024, 256, 0, stream>>>(xh32, bnacc, bng, bnb, cnum0, cden0,
                                        cnum1, cden1, x32, out, scf, bmaxf);
    k_att3<<<1024, 256, 0, stream>>>(x32, scf, bmaxf, cnum1, cden1);

    // ---------------- layer 1 (centroid buf1 -> accumulate buf0) ----------
    k_qbc<<<4, 256, 0, stream>>>(cnum1, cden1, epW1, qb, qc);
    k_P<1><<<2048, 256, 0, stream>>>(xin, x32, epW1, qb, qc, Pb32, Pc32, bnacc);
    hipMemsetAsync(flagcnt, 0, 4, stream);
    k_edge<1><<<2048, 256, 0, stream>>>(x32, src_csr, dst_csr, eord, ewin, ew_csr, unoise,
                                        epW1, epb1, epW2, epb2, alphap, Pb32, Pc32,
                                        flagcnt, flaglist, out);
    k_fix<1><<<64, 256, 0, stream>>>(x32, src_csr, dst_csr, eord, ewin, ew_csr, unoise,
                                     epW1, epb1, epW2, epb2, alphap, Pb32, Pc32,
                                     flagcnt, flaglist, out);
    k_nodeup<1><<<2048, 256, 0, stream>>>(x32, ew_csr, src_csr, rowptr, ginW, ginB,
                                          xh32, bnacc);
    k_att1<1><<<1024, 256, 0, stream>>>(xh32, bnacc, bng, bnb, cnum1, cden1,
                                        cnum0, cden0, x32, out, scf, bmaxf);
    k_att3<<<1024, 256, 0, stream>>>(x32, scf, bmaxf, cnum0, cden0);

    // ---------------- heads + centroid output (centroid = buf0) ----------
    k_head<<<2048, 256, 0, stream>>>(x32, cnum0, cden0, hW1, hb1, hW2, hb2, out);
}